// Round 7
// baseline (519.538 us; speedup 1.0000x reference)
//
#include <hip/hip_runtime.h>

#define NUSER 100000
#define NITEM 50000
#define NTOT  150000
#define DF    512
#define DL    64
#define NNZ_  2400000
#define NBLK  586         // ceil(150000/256)

typedef short bf16x8 __attribute__((ext_vector_type(8)));
typedef float f32x4  __attribute__((ext_vector_type(4)));

__device__ __forceinline__ unsigned short bf16r(float f) {
    unsigned u = __float_as_uint(f);
    return (unsigned short)((u + 0x7FFFu + ((u >> 16) & 1u)) >> 16);
}
__device__ __forceinline__ unsigned pack2(float lo, float hi) {
    return (unsigned)bf16r(lo) | ((unsigned)bf16r(hi) << 16);
}

// ---------------- init: W->Wtb bf16 transpose (blocks 0..127) + user normalize ----------------
__global__ __launch_bounds__(256) void k_init(const float* __restrict__ up,
                                              const float* __restrict__ W,
                                              unsigned short* __restrict__ e0,
                                              unsigned short* __restrict__ Wtb) {
    int b = blockIdx.x;
    if (b < 128) {
        int idx = b * 256 + threadIdx.x;    // 0..32767
        int k = idx >> 6, d = idx & 63;
        Wtb[d * DF + k] = bf16r(W[idx]);
        return;
    }
    int t = (b - 128) * 256 + threadIdx.x;
    float v = up[t];
    float ss = v * v;
    #pragma unroll
    for (int m = 32; m >= 1; m >>= 1) ss += __shfl_xor(ss, m, 64);
    float scale = 1.0f / fmaxf(sqrtf(ss), 1e-12f);
    e0[t] = bf16r(v * scale);
}

// ---------------- items: MFMA bf16 GEMM, wave = 16 rows x 64 dims ----------------
__global__ __launch_bounds__(256) void k_item(const float* __restrict__ F,
                                              const unsigned short* __restrict__ Wtb,
                                              const float* __restrict__ B,
                                              unsigned short* __restrict__ e0) {
    int t = threadIdx.x;
    int w = t >> 6, lane = t & 63;
    int g = lane >> 4;          // k-chunk group 0..3
    int c = lane & 15;          // A-row / B-col / C-col index
    int row_base = blockIdx.x * 64 + w * 16;

    int ar = row_base + c;
    if (ar >= NITEM) ar = NITEM - 1;            // clamp OOB loads; stores guarded later
    const float* Frow = F + (size_t)ar * DF;

    f32x4 acc[4] = {};                          // 4 col-tiles of 16x16
    #pragma unroll 2
    for (int kc = 0; kc < DF; kc += 32) {
        int k0 = kc + g * 8;
        float4 f0 = *(const float4*)&Frow[k0];
        float4 f1 = *(const float4*)&Frow[k0 + 4];
        union { uint4 u; bf16x8 v; } a;
        a.u.x = pack2(f0.x, f0.y);
        a.u.y = pack2(f0.z, f0.w);
        a.u.z = pack2(f1.x, f1.y);
        a.u.w = pack2(f1.z, f1.w);
        #pragma unroll
        for (int ct = 0; ct < 4; ++ct) {
            union { uint4 u; bf16x8 v; } bb;
            bb.u = *(const uint4*)&Wtb[(size_t)(ct * 16 + c) * DF + k0];
            acc[ct] = __builtin_amdgcn_mfma_f32_16x16x32_bf16(a.v, bb.v, acc[ct], 0, 0, 0);
        }
    }

    #pragma unroll
    for (int ct = 0; ct < 4; ++ct) {
        float bc = B[ct * 16 + c];
        #pragma unroll
        for (int r = 0; r < 4; ++r) acc[ct][r] += bc;
    }
    float ssv[4];
    #pragma unroll
    for (int r = 0; r < 4; ++r) {
        float s = acc[0][r] * acc[0][r] + acc[1][r] * acc[1][r]
                + acc[2][r] * acc[2][r] + acc[3][r] * acc[3][r];
        #pragma unroll
        for (int m = 1; m <= 8; m <<= 1) s += __shfl_xor(s, m, 64);
        ssv[r] = 1.0f / fmaxf(sqrtf(s), 1e-12f);
    }
    #pragma unroll
    for (int r = 0; r < 4; ++r) {
        int gr = row_base + g * 4 + r;
        if (gr < NITEM) {
            size_t o = (size_t)(NUSER + gr) * DL + c;
            #pragma unroll
            for (int ct = 0; ct < 4; ++ct)
                e0[o + ct * 16] = bf16r(acc[ct][r] * ssv[r]);
        }
    }
}

// ---------------- per-row histogram (global atomics) ----------------
__global__ __launch_bounds__(256) void k_hist_row(const int* __restrict__ rows,
                                                  int* __restrict__ rowCnt) {
    int e = blockIdx.x * 256 + threadIdx.x;     // grid covers NNZ_ exactly
    atomicAdd(&rowCnt[rows[e]], 1);
}

// ---------------- scan a: per-256-block local exclusive scan + block sums ----------------
__global__ __launch_bounds__(256) void k_scan_a(const int* __restrict__ rowCnt,
                                                int* __restrict__ localEx,
                                                int* __restrict__ blkSum) {
    __shared__ int s[256];
    int b = blockIdx.x, t = threadIdx.x;
    int i = b * 256 + t;
    int x = (i < NTOT) ? rowCnt[i] : 0;
    s[t] = x;
    __syncthreads();
    #pragma unroll
    for (int off = 1; off < 256; off <<= 1) {
        int v = (t >= off) ? s[t - off] : 0;
        __syncthreads();
        s[t] += v;
        __syncthreads();
    }
    if (i < NTOT) localEx[i] = s[t] - x;
    if (t == 255) blkSum[b] = s[255];
}

// ---------------- scan b: single-block exclusive scan of block sums ----------------
__global__ __launch_bounds__(256) void k_scan_b(const int* __restrict__ blkSum,
                                                int* __restrict__ blkBase) {
    __shared__ int s[256];
    __shared__ int carry;
    int t = threadIdx.x;
    if (t == 0) carry = 0;
    __syncthreads();
    for (int base = 0; base < NBLK; base += 256) {
        int idx = base + t;
        int x = (idx < NBLK) ? blkSum[idx] : 0;
        s[t] = x;
        __syncthreads();
        #pragma unroll
        for (int off = 1; off < 256; off <<= 1) {
            int v = (t >= off) ? s[t - off] : 0;
            __syncthreads();
            s[t] += v;
            __syncthreads();
        }
        if (idx < NBLK) blkBase[idx] = carry + s[t] - x;
        __syncthreads();
        if (t == 255) carry += s[255];
        __syncthreads();
    }
}

// ---------------- finalize rowSC + cursor ----------------
__global__ __launch_bounds__(256) void k_fin(const int* __restrict__ rowCnt,
                                             const int* __restrict__ localEx,
                                             const int* __restrict__ blkBase,
                                             int2* __restrict__ rowSC,
                                             int* __restrict__ cursor) {
    int i = blockIdx.x * 256 + threadIdx.x;
    if (i >= NTOT) return;
    int start = blkBase[i >> 8] + localEx[i];
    rowSC[i] = make_int2(start, rowCnt[i]);
    cursor[i] = start;
}

// ---------------- scatter straight into row-sorted CSR ----------------
__global__ __launch_bounds__(256) void k_scatter_row(const int* __restrict__ rows,
                                                     const int* __restrict__ cols,
                                                     const float* __restrict__ vals,
                                                     int* __restrict__ cursor,
                                                     int2* __restrict__ eb2) {
    int e = blockIdx.x * 256 + threadIdx.x;     // grid covers NNZ_ exactly
    int r = rows[e];
    int pos = atomicAdd(&cursor[r], 1);
    eb2[pos] = make_int2(cols[e], __float_as_int(vals[e]));
}

// ---------------- SpMM layer: wave per row, 8 groups, 2-wide unrolled ----------------
__global__ __launch_bounds__(256) void k_spmm_row(const int2* __restrict__ rowSC,
                                                  const int2* __restrict__ eb2,
                                                  const unsigned short* __restrict__ embIn,
                                                  unsigned short* __restrict__ embOut) {
    int wid = (blockIdx.x * 256 + threadIdx.x) >> 6;
    if (wid >= NTOT) return;
    int lane = threadIdx.x & 63;
    int g = lane >> 3, ld = lane & 7;
    int2 sc = rowSC[wid];
    int j = sc.x + g;
    int end = sc.x + sc.y;
    float2 ac[4] = {};
    for (; j + 8 < end; j += 16) {
        int2 eA = eb2[j];
        int2 eB = eb2[j + 8];
        uint4 mA = *(const uint4*)&embIn[(size_t)eA.x * DL + ld * 8];
        uint4 mB = *(const uint4*)&embIn[(size_t)eB.x * DL + ld * 8];
        float vA = __int_as_float(eA.y), vB = __int_as_float(eB.y);
        const unsigned* pA = (const unsigned*)&mA;
        const unsigned* pB = (const unsigned*)&mB;
        #pragma unroll
        for (int k = 0; k < 4; ++k) {
            ac[k].x += vA * __uint_as_float(pA[k] << 16);
            ac[k].y += vA * __uint_as_float(pA[k] & 0xFFFF0000u);
            ac[k].x += vB * __uint_as_float(pB[k] << 16);
            ac[k].y += vB * __uint_as_float(pB[k] & 0xFFFF0000u);
        }
    }
    if (j < end) {
        int2 e = eb2[j];
        uint4 m = *(const uint4*)&embIn[(size_t)e.x * DL + ld * 8];
        float v = __int_as_float(e.y);
        const unsigned* p = (const unsigned*)&m;
        #pragma unroll
        for (int k = 0; k < 4; ++k) {
            ac[k].x += v * __uint_as_float(p[k] << 16);
            ac[k].y += v * __uint_as_float(p[k] & 0xFFFF0000u);
        }
    }
    float acc[8] = {ac[0].x, ac[0].y, ac[1].x, ac[1].y,
                    ac[2].x, ac[2].y, ac[3].x, ac[3].y};
    #pragma unroll
    for (int m = 8; m <= 32; m <<= 1) {
        #pragma unroll
        for (int k = 0; k < 8; ++k) acc[k] += __shfl_xor(acc[k], m, 64);
    }
    if (g == 0) {
        uint4 o;
        o.x = pack2(acc[0], acc[1]);
        o.y = pack2(acc[2], acc[3]);
        o.z = pack2(acc[4], acc[5]);
        o.w = pack2(acc[6], acc[7]);
        *(uint4*)&embOut[(size_t)wid * DL + ld * 8] = o;
    }
}

// ---------------- last layer: same + fused out = 0.25*(e0+e1+e2+acc) ----------------
__global__ __launch_bounds__(256) void k_spmm_last(const int2* __restrict__ rowSC,
                                                   const int2* __restrict__ eb2,
                                                   const unsigned short* __restrict__ e0,
                                                   const unsigned short* __restrict__ e1,
                                                   const unsigned short* __restrict__ e2,
                                                   float* __restrict__ out) {
    int wid = (blockIdx.x * 256 + threadIdx.x) >> 6;
    if (wid >= NTOT) return;
    int lane = threadIdx.x & 63;
    int g = lane >> 3, ld = lane & 7;
    int2 sc = rowSC[wid];
    int j = sc.x + g;
    int end = sc.x + sc.y;
    float2 ac[4] = {};
    for (; j + 8 < end; j += 16) {
        int2 eA = eb2[j];
        int2 eB = eb2[j + 8];
        uint4 mA = *(const uint4*)&e2[(size_t)eA.x * DL + ld * 8];
        uint4 mB = *(const uint4*)&e2[(size_t)eB.x * DL + ld * 8];
        float vA = __int_as_float(eA.y), vB = __int_as_float(eB.y);
        const unsigned* pA = (const unsigned*)&mA;
        const unsigned* pB = (const unsigned*)&mB;
        #pragma unroll
        for (int k = 0; k < 4; ++k) {
            ac[k].x += vA * __uint_as_float(pA[k] << 16);
            ac[k].y += vA * __uint_as_float(pA[k] & 0xFFFF0000u);
            ac[k].x += vB * __uint_as_float(pB[k] << 16);
            ac[k].y += vB * __uint_as_float(pB[k] & 0xFFFF0000u);
        }
    }
    if (j < end) {
        int2 e = eb2[j];
        uint4 m = *(const uint4*)&e2[(size_t)e.x * DL + ld * 8];
        float v = __int_as_float(e.y);
        const unsigned* p = (const unsigned*)&m;
        #pragma unroll
        for (int k = 0; k < 4; ++k) {
            ac[k].x += v * __uint_as_float(p[k] << 16);
            ac[k].y += v * __uint_as_float(p[k] & 0xFFFF0000u);
        }
    }
    float acc[8] = {ac[0].x, ac[0].y, ac[1].x, ac[1].y,
                    ac[2].x, ac[2].y, ac[3].x, ac[3].y};
    #pragma unroll
    for (int m = 8; m <= 32; m <<= 1) {
        #pragma unroll
        for (int k = 0; k < 8; ++k) acc[k] += __shfl_xor(acc[k], m, 64);
    }
    if (g == 0) {
        size_t o = (size_t)wid * DL + ld * 8;
        uint4 a = *(const uint4*)&e0[o];
        uint4 b = *(const uint4*)&e1[o];
        uint4 c = *(const uint4*)&e2[o];
        const unsigned* pa = (const unsigned*)&a;
        const unsigned* pb = (const unsigned*)&b;
        const unsigned* pc = (const unsigned*)&c;
        float r[8];
        #pragma unroll
        for (int k = 0; k < 4; ++k) {
            float lo = __uint_as_float(pa[k] << 16) + __uint_as_float(pb[k] << 16)
                     + __uint_as_float(pc[k] << 16) + acc[2 * k];
            float hi = __uint_as_float(pa[k] & 0xFFFF0000u) + __uint_as_float(pb[k] & 0xFFFF0000u)
                     + __uint_as_float(pc[k] & 0xFFFF0000u) + acc[2 * k + 1];
            r[2 * k]     = 0.25f * lo;
            r[2 * k + 1] = 0.25f * hi;
        }
        *(float4*)&out[o]     = make_float4(r[0], r[1], r[2], r[3]);
        *(float4*)&out[o + 4] = make_float4(r[4], r[5], r[6], r[7]);
    }
}

extern "C" void kernel_launch(void* const* d_in, const int* in_sizes, int n_in,
                              void* d_out, int out_size, void* d_ws, size_t ws_size,
                              hipStream_t stream) {
    const float* F    = (const float*)d_in[0];
    const float* UP   = (const float*)d_in[1];
    const float* W    = (const float*)d_in[2];
    const float* B    = (const float*)d_in[3];
    const int*   rows = (const int*)d_in[4];
    const int*   cols = (const int*)d_in[5];
    const float* vals = (const float*)d_in[6];
    float* out = (float*)d_out;

    // workspace carve (~80 MB)
    unsigned short* e0 = (unsigned short*)d_ws;
    unsigned short* e1 = e0 + (size_t)NTOT * DL;
    unsigned short* e2 = e1 + (size_t)NTOT * DL;
    int2* eb2     = (int2*)(e2 + (size_t)NTOT * DL);
    int2* rowSC   = eb2 + (size_t)NNZ_;
    int*  rowCnt  = (int*)(rowSC + NTOT);
    int*  localEx = rowCnt + NTOT;
    int*  cursor  = localEx + NTOT;
    int*  blkSum  = cursor + NTOT;
    int*  blkBase = blkSum + NBLK;
    unsigned short* Wtb = (unsigned short*)(blkBase + NBLK);  // 64x512 bf16

    hipMemsetAsync(rowCnt, 0, NTOT * sizeof(int), stream);
    k_init<<<128 + (NUSER * DL) / 256, 256, 0, stream>>>(UP, W, e0, Wtb);
    k_item<<<(NITEM + 63) / 64, 256, 0, stream>>>(F, Wtb, B, e0);
    k_hist_row<<<NNZ_ / 256, 256, 0, stream>>>(rows, rowCnt);
    k_scan_a<<<NBLK, 256, 0, stream>>>(rowCnt, localEx, blkSum);
    k_scan_b<<<1, 256, 0, stream>>>(blkSum, blkBase);
    k_fin<<<NBLK, 256, 0, stream>>>(rowCnt, localEx, blkBase, rowSC, cursor);
    k_scatter_row<<<NNZ_ / 256, 256, 0, stream>>>(rows, cols, vals, cursor, eb2);

    k_spmm_row<<<(NTOT * DL) / 256, 256, 0, stream>>>(rowSC, eb2, e0, e1);
    k_spmm_row<<<(NTOT * DL) / 256, 256, 0, stream>>>(rowSC, eb2, e1, e2);
    k_spmm_last<<<(NTOT * DL) / 256, 256, 0, stream>>>(rowSC, eb2, e0, e1, e2, out);
}

// Round 8
// 356.499 us; speedup vs baseline: 1.4573x; 1.4573x over previous
//
#include <hip/hip_runtime.h>

#define NUSER 100000
#define NITEM 50000
#define NTOT  150000
#define DF    512
#define DL    64
#define NNZ_  2400000
#define NB    1172        // ceil(150000/128) row-bins of 128 rows
#define NCHUNK 256
#define CHUNK  9375       // 256*9375 = 2,400,000 exactly

typedef short bf16x8 __attribute__((ext_vector_type(8)));
typedef float f32x4  __attribute__((ext_vector_type(4)));

__device__ __forceinline__ unsigned short bf16r(float f) {
    unsigned u = __float_as_uint(f);
    return (unsigned short)((u + 0x7FFFu + ((u >> 16) & 1u)) >> 16);
}
__device__ __forceinline__ unsigned pack2(float lo, float hi) {
    return (unsigned)bf16r(lo) | ((unsigned)bf16r(hi) << 16);
}

// ---------------- init: W->Wtb bf16 transpose (blocks 0..127) + user normalize ----------------
__global__ __launch_bounds__(256) void k_init(const float* __restrict__ up,
                                              const float* __restrict__ W,
                                              unsigned short* __restrict__ e0,
                                              unsigned short* __restrict__ Wtb) {
    int b = blockIdx.x;
    if (b < 128) {
        int idx = b * 256 + threadIdx.x;    // 0..32767
        int k = idx >> 6, d = idx & 63;
        Wtb[d * DF + k] = bf16r(W[idx]);
        return;
    }
    int t = (b - 128) * 256 + threadIdx.x;
    float v = up[t];
    float ss = v * v;
    #pragma unroll
    for (int m = 32; m >= 1; m >>= 1) ss += __shfl_xor(ss, m, 64);
    float scale = 1.0f / fmaxf(sqrtf(ss), 1e-12f);
    e0[t] = bf16r(v * scale);
}

// ---------------- items: MFMA bf16 GEMM, wave = 16 rows x 64 dims ----------------
__global__ __launch_bounds__(256) void k_item(const float* __restrict__ F,
                                              const unsigned short* __restrict__ Wtb,
                                              const float* __restrict__ B,
                                              unsigned short* __restrict__ e0) {
    int t = threadIdx.x;
    int w = t >> 6, lane = t & 63;
    int g = lane >> 4;          // k-chunk group 0..3
    int c = lane & 15;          // A-row / B-col / C-col index
    int row_base = blockIdx.x * 64 + w * 16;

    int ar = row_base + c;
    if (ar >= NITEM) ar = NITEM - 1;            // clamp OOB loads; stores guarded later
    const float* Frow = F + (size_t)ar * DF;

    f32x4 acc[4] = {};                          // 4 col-tiles of 16x16
    #pragma unroll 2
    for (int kc = 0; kc < DF; kc += 32) {
        int k0 = kc + g * 8;
        float4 f0 = *(const float4*)&Frow[k0];
        float4 f1 = *(const float4*)&Frow[k0 + 4];
        union { uint4 u; bf16x8 v; } a;
        a.u.x = pack2(f0.x, f0.y);
        a.u.y = pack2(f0.z, f0.w);
        a.u.z = pack2(f1.x, f1.y);
        a.u.w = pack2(f1.z, f1.w);
        #pragma unroll
        for (int ct = 0; ct < 4; ++ct) {
            union { uint4 u; bf16x8 v; } bb;
            bb.u = *(const uint4*)&Wtb[(size_t)(ct * 16 + c) * DF + k0];
            acc[ct] = __builtin_amdgcn_mfma_f32_16x16x32_bf16(a.v, bb.v, acc[ct], 0, 0, 0);
        }
    }

    #pragma unroll
    for (int ct = 0; ct < 4; ++ct) {
        float bc = B[ct * 16 + c];
        #pragma unroll
        for (int r = 0; r < 4; ++r) acc[ct][r] += bc;
    }
    float ssv[4];
    #pragma unroll
    for (int r = 0; r < 4; ++r) {
        float s = acc[0][r] * acc[0][r] + acc[1][r] * acc[1][r]
                + acc[2][r] * acc[2][r] + acc[3][r] * acc[3][r];
        #pragma unroll
        for (int m = 1; m <= 8; m <<= 1) s += __shfl_xor(s, m, 64);
        ssv[r] = 1.0f / fmaxf(sqrtf(s), 1e-12f);
    }
    #pragma unroll
    for (int r = 0; r < 4; ++r) {
        int gr = row_base + g * 4 + r;
        if (gr < NITEM) {
            size_t o = (size_t)(NUSER + gr) * DL + c;
            #pragma unroll
            for (int ct = 0; ct < 4; ++ct)
                e0[o + ct * 16] = bf16r(acc[ct][r] * ssv[r]);
        }
    }
}

// ---------------- pass 1: per-chunk histogram over row-bins ----------------
__global__ __launch_bounds__(256) void k_hist(const int* __restrict__ rows,
                                              int* __restrict__ cnt) {
    __shared__ int h[NB];
    int c = blockIdx.x, t = threadIdx.x;
    for (int i = t; i < NB; i += 256) h[i] = 0;
    __syncthreads();
    int end = (c + 1) * CHUNK;
    for (int e = c * CHUNK + t; e < end; e += 256)
        atomicAdd(&h[rows[e] >> 7], 1);
    __syncthreads();
    for (int i = t; i < NB; i += 256) cnt[c * NB + i] = h[i];
}

// ---------------- pass 2a: per-bin exclusive scan over chunks ----------------
__global__ __launch_bounds__(256) void k_scan1(const int* __restrict__ cnt,
                                               int* __restrict__ cntOff,
                                               int* __restrict__ binTot) {
    __shared__ int s[256];
    int b = blockIdx.x, t = threadIdx.x;
    int x = cnt[t * NB + b];
    s[t] = x;
    __syncthreads();
    #pragma unroll
    for (int off = 1; off < 256; off <<= 1) {
        int v = (t >= off) ? s[t - off] : 0;
        __syncthreads();
        s[t] += v;
        __syncthreads();
    }
    cntOff[t * NB + b] = s[t] - x;
    if (t == 255) binTot[b] = s[255];
}

// ---------------- pass 2b: exclusive scan of bin totals ----------------
__global__ __launch_bounds__(256) void k_scan2(const int* __restrict__ binTot,
                                               int* __restrict__ binBase) {
    __shared__ int s[256];
    __shared__ int carry;
    int t = threadIdx.x;
    if (t == 0) carry = 0;
    __syncthreads();
    for (int base = 0; base < NB; base += 256) {
        int idx = base + t;
        int x = (idx < NB) ? binTot[idx] : 0;
        s[t] = x;
        __syncthreads();
        #pragma unroll
        for (int off = 1; off < 256; off <<= 1) {
            int v = (t >= off) ? s[t - off] : 0;
            __syncthreads();
            s[t] += v;
            __syncthreads();
        }
        if (idx < NB) binBase[idx] = carry + s[t] - x;
        __syncthreads();
        if (t == 255) carry += s[255];
        __syncthreads();
    }
    if (t == 0) binBase[NB] = carry;   // == NNZ
}

// ---------------- pass 3: scatter edges into bin-partitioned list ----------------
__global__ __launch_bounds__(256) void k_scatter(const int* __restrict__ rows,
                                                 const int* __restrict__ cols,
                                                 const float* __restrict__ vals,
                                                 const int* __restrict__ cntOff,
                                                 const int* __restrict__ binBase,
                                                 int2* __restrict__ eb) {
    __shared__ int cur[NB];
    int c = blockIdx.x, t = threadIdx.x;
    for (int i = t; i < NB; i += 256) cur[i] = binBase[i] + cntOff[c * NB + i];
    __syncthreads();
    int end = (c + 1) * CHUNK;
    for (int e = c * CHUNK + t; e < end; e += 256) {
        int r = rows[e];
        int b = r >> 7;
        int pos = atomicAdd(&cur[b], 1);
        eb[pos] = make_int2(cols[e] | ((r & 127) << 18), __float_as_int(vals[e]));
    }
}

// ---------------- pass 4: per-bin counting sort -> exact row-sorted CSR ----------------
__global__ __launch_bounds__(256) void k_binsort(const int2* __restrict__ eb,
                                                 const int* __restrict__ binBase,
                                                 int2* __restrict__ eb2,
                                                 int2* __restrict__ rowSC) {
    __shared__ int h[128];
    __shared__ int s[128];
    int b = blockIdx.x, t = threadIdx.x;
    if (t < 128) h[t] = 0;
    __syncthreads();
    int base = binBase[b];
    int cnt  = binBase[b + 1] - base;
    for (int j = t; j < cnt; j += 256)
        atomicAdd(&h[eb[base + j].x >> 18], 1);
    __syncthreads();
    if (t < 128) s[t] = h[t];
    __syncthreads();
    #pragma unroll
    for (int off = 1; off < 128; off <<= 1) {
        int v = 0;
        if (t < 128 && t >= off) v = s[t - off];
        __syncthreads();
        if (t < 128) s[t] += v;
        __syncthreads();
    }
    if (t < 128) {
        int e = s[t] - h[t];       // exclusive within-bin offset
        int r = (b << 7) + t;
        if (r < NTOT) rowSC[r] = make_int2(base + e, h[t]);
        s[t] = e;                  // becomes the cursor
    }
    __syncthreads();
    for (int j = t; j < cnt; j += 256) {
        int2 e = eb[base + j];
        int rl = e.x >> 18;
        int pos = base + atomicAdd(&s[rl], 1);
        eb2[pos] = make_int2(e.x & 0x3FFFF, e.y);
    }
}

// ---------------- SpMM layer: wave per row, 8 groups, 2-wide unrolled ----------------
__global__ __launch_bounds__(256) void k_spmm_row(const int2* __restrict__ rowSC,
                                                  const int2* __restrict__ eb2,
                                                  const unsigned short* __restrict__ embIn,
                                                  unsigned short* __restrict__ embOut) {
    int wid = (blockIdx.x * 256 + threadIdx.x) >> 6;
    if (wid >= NTOT) return;
    int lane = threadIdx.x & 63;
    int g = lane >> 3, ld = lane & 7;
    int2 sc = rowSC[wid];
    int j = sc.x + g;
    int end = sc.x + sc.y;
    float2 ac[4] = {};
    for (; j + 8 < end; j += 16) {
        int2 eA = eb2[j];
        int2 eB = eb2[j + 8];
        uint4 mA = *(const uint4*)&embIn[(size_t)eA.x * DL + ld * 8];
        uint4 mB = *(const uint4*)&embIn[(size_t)eB.x * DL + ld * 8];
        float vA = __int_as_float(eA.y), vB = __int_as_float(eB.y);
        const unsigned* pA = (const unsigned*)&mA;
        const unsigned* pB = (const unsigned*)&mB;
        #pragma unroll
        for (int k = 0; k < 4; ++k) {
            ac[k].x += vA * __uint_as_float(pA[k] << 16);
            ac[k].y += vA * __uint_as_float(pA[k] & 0xFFFF0000u);
            ac[k].x += vB * __uint_as_float(pB[k] << 16);
            ac[k].y += vB * __uint_as_float(pB[k] & 0xFFFF0000u);
        }
    }
    if (j < end) {
        int2 e = eb2[j];
        uint4 m = *(const uint4*)&embIn[(size_t)e.x * DL + ld * 8];
        float v = __int_as_float(e.y);
        const unsigned* p = (const unsigned*)&m;
        #pragma unroll
        for (int k = 0; k < 4; ++k) {
            ac[k].x += v * __uint_as_float(p[k] << 16);
            ac[k].y += v * __uint_as_float(p[k] & 0xFFFF0000u);
        }
    }
    float acc[8] = {ac[0].x, ac[0].y, ac[1].x, ac[1].y,
                    ac[2].x, ac[2].y, ac[3].x, ac[3].y};
    #pragma unroll
    for (int m = 8; m <= 32; m <<= 1) {
        #pragma unroll
        for (int k = 0; k < 8; ++k) acc[k] += __shfl_xor(acc[k], m, 64);
    }
    if (g == 0) {
        uint4 o;
        o.x = pack2(acc[0], acc[1]);
        o.y = pack2(acc[2], acc[3]);
        o.z = pack2(acc[4], acc[5]);
        o.w = pack2(acc[6], acc[7]);
        *(uint4*)&embOut[(size_t)wid * DL + ld * 8] = o;
    }
}

// ---------------- last layer: same + fused out = 0.25*(e0+e1+e2+acc) ----------------
__global__ __launch_bounds__(256) void k_spmm_last(const int2* __restrict__ rowSC,
                                                   const int2* __restrict__ eb2,
                                                   const unsigned short* __restrict__ e0,
                                                   const unsigned short* __restrict__ e1,
                                                   const unsigned short* __restrict__ e2,
                                                   float* __restrict__ out) {
    int wid = (blockIdx.x * 256 + threadIdx.x) >> 6;
    if (wid >= NTOT) return;
    int lane = threadIdx.x & 63;
    int g = lane >> 3, ld = lane & 7;
    int2 sc = rowSC[wid];
    int j = sc.x + g;
    int end = sc.x + sc.y;
    float2 ac[4] = {};
    for (; j + 8 < end; j += 16) {
        int2 eA = eb2[j];
        int2 eB = eb2[j + 8];
        uint4 mA = *(const uint4*)&e2[(size_t)eA.x * DL + ld * 8];
        uint4 mB = *(const uint4*)&e2[(size_t)eB.x * DL + ld * 8];
        float vA = __int_as_float(eA.y), vB = __int_as_float(eB.y);
        const unsigned* pA = (const unsigned*)&mA;
        const unsigned* pB = (const unsigned*)&mB;
        #pragma unroll
        for (int k = 0; k < 4; ++k) {
            ac[k].x += vA * __uint_as_float(pA[k] << 16);
            ac[k].y += vA * __uint_as_float(pA[k] & 0xFFFF0000u);
            ac[k].x += vB * __uint_as_float(pB[k] << 16);
            ac[k].y += vB * __uint_as_float(pB[k] & 0xFFFF0000u);
        }
    }
    if (j < end) {
        int2 e = eb2[j];
        uint4 m = *(const uint4*)&e2[(size_t)e.x * DL + ld * 8];
        float v = __int_as_float(e.y);
        const unsigned* p = (const unsigned*)&m;
        #pragma unroll
        for (int k = 0; k < 4; ++k) {
            ac[k].x += v * __uint_as_float(p[k] << 16);
            ac[k].y += v * __uint_as_float(p[k] & 0xFFFF0000u);
        }
    }
    float acc[8] = {ac[0].x, ac[0].y, ac[1].x, ac[1].y,
                    ac[2].x, ac[2].y, ac[3].x, ac[3].y};
    #pragma unroll
    for (int m = 8; m <= 32; m <<= 1) {
        #pragma unroll
        for (int k = 0; k < 8; ++k) acc[k] += __shfl_xor(acc[k], m, 64);
    }
    if (g == 0) {
        size_t o = (size_t)wid * DL + ld * 8;
        uint4 a = *(const uint4*)&e0[o];
        uint4 b = *(const uint4*)&e1[o];
        uint4 c = *(const uint4*)&e2[o];
        const unsigned* pa = (const unsigned*)&a;
        const unsigned* pb = (const unsigned*)&b;
        const unsigned* pc = (const unsigned*)&c;
        float r[8];
        #pragma unroll
        for (int k = 0; k < 4; ++k) {
            float lo = __uint_as_float(pa[k] << 16) + __uint_as_float(pb[k] << 16)
                     + __uint_as_float(pc[k] << 16) + acc[2 * k];
            float hi = __uint_as_float(pa[k] & 0xFFFF0000u) + __uint_as_float(pb[k] & 0xFFFF0000u)
                     + __uint_as_float(pc[k] & 0xFFFF0000u) + acc[2 * k + 1];
            r[2 * k]     = 0.25f * lo;
            r[2 * k + 1] = 0.25f * hi;
        }
        *(float4*)&out[o]     = make_float4(r[0], r[1], r[2], r[3]);
        *(float4*)&out[o + 4] = make_float4(r[4], r[5], r[6], r[7]);
    }
}

extern "C" void kernel_launch(void* const* d_in, const int* in_sizes, int n_in,
                              void* d_out, int out_size, void* d_ws, size_t ws_size,
                              hipStream_t stream) {
    const float* F    = (const float*)d_in[0];
    const float* UP   = (const float*)d_in[1];
    const float* W    = (const float*)d_in[2];
    const float* B    = (const float*)d_in[3];
    const int*   rows = (const int*)d_in[4];
    const int*   cols = (const int*)d_in[5];
    const float* vals = (const float*)d_in[6];
    float* out = (float*)d_out;

    // workspace carve (~100 MB)
    unsigned short* e0 = (unsigned short*)d_ws;
    unsigned short* e1 = e0 + (size_t)NTOT * DL;
    unsigned short* e2 = e1 + (size_t)NTOT * DL;
    int2* eb      = (int2*)(e2 + (size_t)NTOT * DL);
    int2* eb2     = eb + (size_t)NNZ_;
    int2* rowSC   = eb2 + (size_t)NNZ_;
    int*  cnt     = (int*)(rowSC + NTOT);
    int*  cntOff  = cnt + (size_t)NCHUNK * NB;
    int*  binTot  = cntOff + (size_t)NCHUNK * NB;
    int*  binBase = binTot + NB;                      // NB+1 entries
    unsigned short* Wtb = (unsigned short*)(binBase + NB + 1);  // 64x512 bf16

    k_init<<<128 + (NUSER * DL) / 256, 256, 0, stream>>>(UP, W, e0, Wtb);
    k_item<<<(NITEM + 63) / 64, 256, 0, stream>>>(F, Wtb, B, e0);
    k_hist<<<NCHUNK, 256, 0, stream>>>(rows, cnt);
    k_scan1<<<NB, 256, 0, stream>>>(cnt, cntOff, binTot);
    k_scan2<<<1, 256, 0, stream>>>(binTot, binBase);
    k_scatter<<<NCHUNK, 256, 0, stream>>>(rows, cols, vals, cntOff, binBase, eb);
    k_binsort<<<NB, 256, 0, stream>>>(eb, binBase, eb2, rowSC);

    k_spmm_row<<<(NTOT * DL) / 256, 256, 0, stream>>>(rowSC, eb2, e0, e1);
    k_spmm_row<<<(NTOT * DL) / 256, 256, 0, stream>>>(rowSC, eb2, e1, e2);
    k_spmm_last<<<(NTOT * DL) / 256, 256, 0, stream>>>(rowSC, eb2, e0, e1, e2, out);
}

// Round 9
// 338.935 us; speedup vs baseline: 1.5329x; 1.0518x over previous
//
#include <hip/hip_runtime.h>

#define NUSER 100000
#define NITEM 50000
#define NTOT  150000
#define DF    512
#define DL    64
#define NNZ_  2400000
#define NB    1172        // ceil(150000/128) row-bins of 128 rows
#define NCHUNK 256
#define CHUNK  9375       // 256*9375 = 2,400,000 exactly

typedef short bf16x8 __attribute__((ext_vector_type(8)));
typedef float f32x4  __attribute__((ext_vector_type(4)));

__device__ __forceinline__ unsigned short bf16r(float f) {
    unsigned u = __float_as_uint(f);
    return (unsigned short)((u + 0x7FFFu + ((u >> 16) & 1u)) >> 16);
}
__device__ __forceinline__ unsigned pack2(float lo, float hi) {
    return (unsigned)bf16r(lo) | ((unsigned)bf16r(hi) << 16);
}
__device__ __forceinline__ float blo(unsigned u) { return __uint_as_float(u << 16); }
__device__ __forceinline__ float bhi(unsigned u) { return __uint_as_float(u & 0xFFFF0000u); }

// ---------------- init: W->Wtb bf16 transpose (blocks 0..127) + user normalize ----------------
__global__ __launch_bounds__(256) void k_init(const float* __restrict__ up,
                                              const float* __restrict__ W,
                                              unsigned short* __restrict__ e0,
                                              unsigned short* __restrict__ Wtb) {
    int b = blockIdx.x;
    if (b < 128) {
        int idx = b * 256 + threadIdx.x;    // 0..32767
        int k = idx >> 6, d = idx & 63;
        Wtb[d * DF + k] = bf16r(W[idx]);
        return;
    }
    int t = (b - 128) * 256 + threadIdx.x;
    float v = up[t];
    float ss = v * v;
    #pragma unroll
    for (int m = 32; m >= 1; m >>= 1) ss += __shfl_xor(ss, m, 64);
    float scale = 1.0f / fmaxf(sqrtf(ss), 1e-12f);
    e0[t] = bf16r(v * scale);
}

// ---------------- items: MFMA bf16 GEMM, wave = 16 rows x 64 dims ----------------
__global__ __launch_bounds__(256) void k_item(const float* __restrict__ F,
                                              const unsigned short* __restrict__ Wtb,
                                              const float* __restrict__ B,
                                              unsigned short* __restrict__ e0) {
    int t = threadIdx.x;
    int w = t >> 6, lane = t & 63;
    int g = lane >> 4;          // k-chunk group 0..3
    int c = lane & 15;          // A-row / B-col / C-col index
    int row_base = blockIdx.x * 64 + w * 16;

    int ar = row_base + c;
    if (ar >= NITEM) ar = NITEM - 1;            // clamp OOB loads; stores guarded later
    const float* Frow = F + (size_t)ar * DF;

    f32x4 acc[4] = {};                          // 4 col-tiles of 16x16
    #pragma unroll 2
    for (int kc = 0; kc < DF; kc += 32) {
        int k0 = kc + g * 8;
        float4 f0 = *(const float4*)&Frow[k0];
        float4 f1 = *(const float4*)&Frow[k0 + 4];
        union { uint4 u; bf16x8 v; } a;
        a.u.x = pack2(f0.x, f0.y);
        a.u.y = pack2(f0.z, f0.w);
        a.u.z = pack2(f1.x, f1.y);
        a.u.w = pack2(f1.z, f1.w);
        #pragma unroll
        for (int ct = 0; ct < 4; ++ct) {
            union { uint4 u; bf16x8 v; } bb;
            bb.u = *(const uint4*)&Wtb[(size_t)(ct * 16 + c) * DF + k0];
            acc[ct] = __builtin_amdgcn_mfma_f32_16x16x32_bf16(a.v, bb.v, acc[ct], 0, 0, 0);
        }
    }

    #pragma unroll
    for (int ct = 0; ct < 4; ++ct) {
        float bc = B[ct * 16 + c];
        #pragma unroll
        for (int r = 0; r < 4; ++r) acc[ct][r] += bc;
    }
    float ssv[4];
    #pragma unroll
    for (int r = 0; r < 4; ++r) {
        float s = acc[0][r] * acc[0][r] + acc[1][r] * acc[1][r]
                + acc[2][r] * acc[2][r] + acc[3][r] * acc[3][r];
        #pragma unroll
        for (int m = 1; m <= 8; m <<= 1) s += __shfl_xor(s, m, 64);
        ssv[r] = 1.0f / fmaxf(sqrtf(s), 1e-12f);
    }
    #pragma unroll
    for (int r = 0; r < 4; ++r) {
        int gr = row_base + g * 4 + r;
        if (gr < NITEM) {
            size_t o = (size_t)(NUSER + gr) * DL + c;
            #pragma unroll
            for (int ct = 0; ct < 4; ++ct)
                e0[o + ct * 16] = bf16r(acc[ct][r] * ssv[r]);
        }
    }
}

// ---------------- pass 1: per-chunk histogram over row-bins ----------------
__global__ __launch_bounds__(256) void k_hist(const int* __restrict__ rows,
                                              int* __restrict__ cnt) {
    __shared__ int h[NB];
    int c = blockIdx.x, t = threadIdx.x;
    for (int i = t; i < NB; i += 256) h[i] = 0;
    __syncthreads();
    int end = (c + 1) * CHUNK;
    for (int e = c * CHUNK + t; e < end; e += 256)
        atomicAdd(&h[rows[e] >> 7], 1);
    __syncthreads();
    for (int i = t; i < NB; i += 256) cnt[c * NB + i] = h[i];
}

// ---------------- pass 2a: per-bin exclusive scan over chunks ----------------
__global__ __launch_bounds__(256) void k_scan1(const int* __restrict__ cnt,
                                               int* __restrict__ cntOff,
                                               int* __restrict__ binTot) {
    __shared__ int s[256];
    int b = blockIdx.x, t = threadIdx.x;
    int x = cnt[t * NB + b];
    s[t] = x;
    __syncthreads();
    #pragma unroll
    for (int off = 1; off < 256; off <<= 1) {
        int v = (t >= off) ? s[t - off] : 0;
        __syncthreads();
        s[t] += v;
        __syncthreads();
    }
    cntOff[t * NB + b] = s[t] - x;
    if (t == 255) binTot[b] = s[255];
}

// ---------------- pass 2b: exclusive scan of bin totals ----------------
__global__ __launch_bounds__(256) void k_scan2(const int* __restrict__ binTot,
                                               int* __restrict__ binBase) {
    __shared__ int s[256];
    __shared__ int carry;
    int t = threadIdx.x;
    if (t == 0) carry = 0;
    __syncthreads();
    for (int base = 0; base < NB; base += 256) {
        int idx = base + t;
        int x = (idx < NB) ? binTot[idx] : 0;
        s[t] = x;
        __syncthreads();
        #pragma unroll
        for (int off = 1; off < 256; off <<= 1) {
            int v = (t >= off) ? s[t - off] : 0;
            __syncthreads();
            s[t] += v;
            __syncthreads();
        }
        if (idx < NB) binBase[idx] = carry + s[t] - x;
        __syncthreads();
        if (t == 255) carry += s[255];
        __syncthreads();
    }
    if (t == 0) binBase[NB] = carry;   // == NNZ
}

// ---------------- pass 3: scatter edges into bin-partitioned list ----------------
__global__ __launch_bounds__(256) void k_scatter(const int* __restrict__ rows,
                                                 const int* __restrict__ cols,
                                                 const float* __restrict__ vals,
                                                 const int* __restrict__ cntOff,
                                                 const int* __restrict__ binBase,
                                                 int2* __restrict__ eb) {
    __shared__ int cur[NB];
    int c = blockIdx.x, t = threadIdx.x;
    for (int i = t; i < NB; i += 256) cur[i] = binBase[i] + cntOff[c * NB + i];
    __syncthreads();
    int end = (c + 1) * CHUNK;
    for (int e = c * CHUNK + t; e < end; e += 256) {
        int r = rows[e];
        int b = r >> 7;
        int pos = atomicAdd(&cur[b], 1);
        eb[pos] = make_int2(cols[e] | ((r & 127) << 18), __float_as_int(vals[e]));
    }
}

// ---------------- pass 4: per-bin counting sort -> exact row-sorted CSR ----------------
__global__ __launch_bounds__(256) void k_binsort(const int2* __restrict__ eb,
                                                 const int* __restrict__ binBase,
                                                 int2* __restrict__ eb2,
                                                 int2* __restrict__ rowSC) {
    __shared__ int h[128];
    __shared__ int s[128];
    int b = blockIdx.x, t = threadIdx.x;
    if (t < 128) h[t] = 0;
    __syncthreads();
    int base = binBase[b];
    int cnt  = binBase[b + 1] - base;
    for (int j = t; j < cnt; j += 256)
        atomicAdd(&h[eb[base + j].x >> 18], 1);
    __syncthreads();
    if (t < 128) s[t] = h[t];
    __syncthreads();
    #pragma unroll
    for (int off = 1; off < 128; off <<= 1) {
        int v = 0;
        if (t < 128 && t >= off) v = s[t - off];
        __syncthreads();
        if (t < 128) s[t] += v;
        __syncthreads();
    }
    if (t < 128) {
        int e = s[t] - h[t];       // exclusive within-bin offset
        int r = (b << 7) + t;
        if (r < NTOT) rowSC[r] = make_int2(base + e, h[t]);
        s[t] = e;                  // becomes the cursor
    }
    __syncthreads();
    for (int j = t; j < cnt; j += 256) {
        int2 e = eb[base + j];
        int rl = e.x >> 18;
        int pos = base + atomicAdd(&s[rl], 1);
        eb2[pos] = make_int2(e.x & 0x3FFFF, e.y);
    }
}

// ---------------- SpMM layer: 16 lanes per row (4 rows/wave), 4-wide pipeline ----------------
__global__ __launch_bounds__(256) void k_spmm_row(const int2* __restrict__ rowSC,
                                                  const int2* __restrict__ eb2,
                                                  const unsigned short* __restrict__ embIn,
                                                  unsigned short* __restrict__ embOut) {
    int gt = blockIdx.x * 256 + threadIdx.x;
    int r  = gt >> 4;                 // row, one per 16-lane group
    if (r >= NTOT) return;
    int lq = threadIdx.x & 15;        // 4 dims per lane
    int2 sc = rowSC[r];
    int j = sc.x, end = sc.x + sc.y;
    float a0 = 0.f, a1 = 0.f, a2 = 0.f, a3 = 0.f;
    int doff = lq * 4;
    for (; j + 3 < end; j += 4) {
        int2 eA = eb2[j],     eB = eb2[j + 1];
        int2 eC = eb2[j + 2], eD = eb2[j + 3];
        uint2 mA = *(const uint2*)&embIn[eA.x * DL + doff];
        uint2 mB = *(const uint2*)&embIn[eB.x * DL + doff];
        uint2 mC = *(const uint2*)&embIn[eC.x * DL + doff];
        uint2 mD = *(const uint2*)&embIn[eD.x * DL + doff];
        float vA = __int_as_float(eA.y), vB = __int_as_float(eB.y);
        float vC = __int_as_float(eC.y), vD = __int_as_float(eD.y);
        a0 += vA * blo(mA.x); a1 += vA * bhi(mA.x); a2 += vA * blo(mA.y); a3 += vA * bhi(mA.y);
        a0 += vB * blo(mB.x); a1 += vB * bhi(mB.x); a2 += vB * blo(mB.y); a3 += vB * bhi(mB.y);
        a0 += vC * blo(mC.x); a1 += vC * bhi(mC.x); a2 += vC * blo(mC.y); a3 += vC * bhi(mC.y);
        a0 += vD * blo(mD.x); a1 += vD * bhi(mD.x); a2 += vD * blo(mD.y); a3 += vD * bhi(mD.y);
    }
    for (; j < end; ++j) {
        int2 e = eb2[j];
        uint2 m = *(const uint2*)&embIn[e.x * DL + doff];
        float v = __int_as_float(e.y);
        a0 += v * blo(m.x); a1 += v * bhi(m.x); a2 += v * blo(m.y); a3 += v * bhi(m.y);
    }
    uint2 o;
    o.x = pack2(a0, a1);
    o.y = pack2(a2, a3);
    *(uint2*)&embOut[r * DL + doff] = o;
}

// ---------------- last layer: same + fused out = 0.25*(e0+e1+e2+acc) ----------------
__global__ __launch_bounds__(256) void k_spmm_last(const int2* __restrict__ rowSC,
                                                   const int2* __restrict__ eb2,
                                                   const unsigned short* __restrict__ e0,
                                                   const unsigned short* __restrict__ e1,
                                                   const unsigned short* __restrict__ e2,
                                                   float* __restrict__ out) {
    int gt = blockIdx.x * 256 + threadIdx.x;
    int r  = gt >> 4;
    if (r >= NTOT) return;
    int lq = threadIdx.x & 15;
    int2 sc = rowSC[r];
    int j = sc.x, end = sc.x + sc.y;
    float a0 = 0.f, a1 = 0.f, a2 = 0.f, a3 = 0.f;
    int doff = lq * 4;
    for (; j + 3 < end; j += 4) {
        int2 eA = eb2[j],     eB = eb2[j + 1];
        int2 eC = eb2[j + 2], eD = eb2[j + 3];
        uint2 mA = *(const uint2*)&e2[eA.x * DL + doff];
        uint2 mB = *(const uint2*)&e2[eB.x * DL + doff];
        uint2 mC = *(const uint2*)&e2[eC.x * DL + doff];
        uint2 mD = *(const uint2*)&e2[eD.x * DL + doff];
        float vA = __int_as_float(eA.y), vB = __int_as_float(eB.y);
        float vC = __int_as_float(eC.y), vD = __int_as_float(eD.y);
        a0 += vA * blo(mA.x); a1 += vA * bhi(mA.x); a2 += vA * blo(mA.y); a3 += vA * bhi(mA.y);
        a0 += vB * blo(mB.x); a1 += vB * bhi(mB.x); a2 += vB * blo(mB.y); a3 += vB * bhi(mB.y);
        a0 += vC * blo(mC.x); a1 += vC * bhi(mC.x); a2 += vC * blo(mC.y); a3 += vC * bhi(mC.y);
        a0 += vD * blo(mD.x); a1 += vD * bhi(mD.x); a2 += vD * blo(mD.y); a3 += vD * bhi(mD.y);
    }
    for (; j < end; ++j) {
        int2 e = eb2[j];
        uint2 m = *(const uint2*)&e2[e.x * DL + doff];
        float v = __int_as_float(e.y);
        a0 += v * blo(m.x); a1 += v * bhi(m.x); a2 += v * blo(m.y); a3 += v * bhi(m.y);
    }
    int o = r * DL + doff;
    uint2 ua = *(const uint2*)&e0[o];
    uint2 ub = *(const uint2*)&e1[o];
    uint2 uc = *(const uint2*)&e2[o];
    float4 res;
    res.x = 0.25f * (blo(ua.x) + blo(ub.x) + blo(uc.x) + a0);
    res.y = 0.25f * (bhi(ua.x) + bhi(ub.x) + bhi(uc.x) + a1);
    res.z = 0.25f * (blo(ua.y) + blo(ub.y) + blo(uc.y) + a2);
    res.w = 0.25f * (bhi(ua.y) + bhi(ub.y) + bhi(uc.y) + a3);
    *(float4*)&out[o] = res;
}

extern "C" void kernel_launch(void* const* d_in, const int* in_sizes, int n_in,
                              void* d_out, int out_size, void* d_ws, size_t ws_size,
                              hipStream_t stream) {
    const float* F    = (const float*)d_in[0];
    const float* UP   = (const float*)d_in[1];
    const float* W    = (const float*)d_in[2];
    const float* B    = (const float*)d_in[3];
    const int*   rows = (const int*)d_in[4];
    const int*   cols = (const int*)d_in[5];
    const float* vals = (const float*)d_in[6];
    float* out = (float*)d_out;

    // workspace carve (~100 MB)
    unsigned short* e0 = (unsigned short*)d_ws;
    unsigned short* e1 = e0 + (size_t)NTOT * DL;
    unsigned short* e2 = e1 + (size_t)NTOT * DL;
    int2* eb      = (int2*)(e2 + (size_t)NTOT * DL);
    int2* eb2     = eb + (size_t)NNZ_;
    int2* rowSC   = eb2 + (size_t)NNZ_;
    int*  cnt     = (int*)(rowSC + NTOT);
    int*  cntOff  = cnt + (size_t)NCHUNK * NB;
    int*  binTot  = cntOff + (size_t)NCHUNK * NB;
    int*  binBase = binTot + NB;                      // NB+1 entries
    unsigned short* Wtb = (unsigned short*)(binBase + NB + 1);  // 64x512 bf16

    k_init<<<128 + (NUSER * DL) / 256, 256, 0, stream>>>(UP, W, e0, Wtb);
    k_item<<<(NITEM + 63) / 64, 256, 0, stream>>>(F, Wtb, B, e0);
    k_hist<<<NCHUNK, 256, 0, stream>>>(rows, cnt);
    k_scan1<<<NB, 256, 0, stream>>>(cnt, cntOff, binTot);
    k_scan2<<<1, 256, 0, stream>>>(binTot, binBase);
    k_scatter<<<NCHUNK, 256, 0, stream>>>(rows, cols, vals, cntOff, binBase, eb);
    k_binsort<<<NB, 256, 0, stream>>>(eb, binBase, eb2, rowSC);

    int spmm_blocks = (NTOT * 16 + 255) / 256;   // 16 threads per row
    k_spmm_row<<<spmm_blocks, 256, 0, stream>>>(rowSC, eb2, e0, e1);
    k_spmm_row<<<spmm_blocks, 256, 0, stream>>>(rowSC, eb2, e1, e2);
    k_spmm_last<<<spmm_blocks, 256, 0, stream>>>(rowSC, eb2, e0, e1, e2, out);
}

// Round 10
// 311.603 us; speedup vs baseline: 1.6673x; 1.0877x over previous
//
#include <hip/hip_runtime.h>

#define NUSER 100000
#define NITEM 50000
#define NTOT  150000
#define DF    512
#define DL    64
#define NNZ_  2400000
#define NB    1172        // ceil(150000/128) row-bins of 128 rows
#define NCHUNK 256
#define CHUNK  9375       // 256*9375 = 2,400,000 exactly

typedef short bf16x8 __attribute__((ext_vector_type(8)));
typedef float f32x4  __attribute__((ext_vector_type(4)));

__device__ __forceinline__ unsigned short bf16r(float f) {
    unsigned u = __float_as_uint(f);
    return (unsigned short)((u + 0x7FFFu + ((u >> 16) & 1u)) >> 16);
}
__device__ __forceinline__ unsigned pack2(float lo, float hi) {
    return (unsigned)bf16r(lo) | ((unsigned)bf16r(hi) << 16);
}
__device__ __forceinline__ float blo(unsigned u) { return __uint_as_float(u << 16); }
__device__ __forceinline__ float bhi(unsigned u) { return __uint_as_float(u & 0xFFFF0000u); }

// ---------------- init: W->Wtb bf16 transpose (blocks 0..127) + user normalize ----------------
__global__ __launch_bounds__(256) void k_init(const float* __restrict__ up,
                                              const float* __restrict__ W,
                                              unsigned short* __restrict__ e0,
                                              unsigned short* __restrict__ Wtb) {
    int b = blockIdx.x;
    if (b < 128) {
        int idx = b * 256 + threadIdx.x;    // 0..32767
        int k = idx >> 6, d = idx & 63;
        Wtb[d * DF + k] = bf16r(W[idx]);
        return;
    }
    int t = (b - 128) * 256 + threadIdx.x;
    float v = up[t];
    float ss = v * v;
    #pragma unroll
    for (int m = 32; m >= 1; m >>= 1) ss += __shfl_xor(ss, m, 64);
    float scale = 1.0f / fmaxf(sqrtf(ss), 1e-12f);
    e0[t] = bf16r(v * scale);
}

// ---------------- items: MFMA bf16 GEMM, wave = 16 rows x 64 dims ----------------
__global__ __launch_bounds__(256) void k_item(const float* __restrict__ F,
                                              const unsigned short* __restrict__ Wtb,
                                              const float* __restrict__ B,
                                              unsigned short* __restrict__ e0) {
    int t = threadIdx.x;
    int w = t >> 6, lane = t & 63;
    int g = lane >> 4;          // k-chunk group 0..3
    int c = lane & 15;          // A-row / B-col / C-col index
    int row_base = blockIdx.x * 64 + w * 16;

    int ar = row_base + c;
    if (ar >= NITEM) ar = NITEM - 1;            // clamp OOB loads; stores guarded later
    const float* Frow = F + (size_t)ar * DF;

    f32x4 acc[4] = {};                          // 4 col-tiles of 16x16
    #pragma unroll 2
    for (int kc = 0; kc < DF; kc += 32) {
        int k0 = kc + g * 8;
        float4 f0 = *(const float4*)&Frow[k0];
        float4 f1 = *(const float4*)&Frow[k0 + 4];
        union { uint4 u; bf16x8 v; } a;
        a.u.x = pack2(f0.x, f0.y);
        a.u.y = pack2(f0.z, f0.w);
        a.u.z = pack2(f1.x, f1.y);
        a.u.w = pack2(f1.z, f1.w);
        #pragma unroll
        for (int ct = 0; ct < 4; ++ct) {
            union { uint4 u; bf16x8 v; } bb;
            bb.u = *(const uint4*)&Wtb[(size_t)(ct * 16 + c) * DF + k0];
            acc[ct] = __builtin_amdgcn_mfma_f32_16x16x32_bf16(a.v, bb.v, acc[ct], 0, 0, 0);
        }
    }

    #pragma unroll
    for (int ct = 0; ct < 4; ++ct) {
        float bc = B[ct * 16 + c];
        #pragma unroll
        for (int r = 0; r < 4; ++r) acc[ct][r] += bc;
    }
    float ssv[4];
    #pragma unroll
    for (int r = 0; r < 4; ++r) {
        float s = acc[0][r] * acc[0][r] + acc[1][r] * acc[1][r]
                + acc[2][r] * acc[2][r] + acc[3][r] * acc[3][r];
        #pragma unroll
        for (int m = 1; m <= 8; m <<= 1) s += __shfl_xor(s, m, 64);
        ssv[r] = 1.0f / fmaxf(sqrtf(s), 1e-12f);
    }
    #pragma unroll
    for (int r = 0; r < 4; ++r) {
        int gr = row_base + g * 4 + r;
        if (gr < NITEM) {
            size_t o = (size_t)(NUSER + gr) * DL + c;
            #pragma unroll
            for (int ct = 0; ct < 4; ++ct)
                e0[o + ct * 16] = bf16r(acc[ct][r] * ssv[r]);
        }
    }
}

// ---------------- pass 1: per-chunk histogram over row-bins (1024 threads) ----------------
__global__ __launch_bounds__(1024) void k_hist(const int* __restrict__ rows,
                                               int* __restrict__ cnt) {
    __shared__ int h[NB];
    int c = blockIdx.x, t = threadIdx.x;
    for (int i = t; i < NB; i += 1024) h[i] = 0;
    __syncthreads();
    int end = (c + 1) * CHUNK;
    for (int e = c * CHUNK + t; e < end; e += 1024)
        atomicAdd(&h[rows[e] >> 7], 1);
    __syncthreads();
    for (int i = t; i < NB; i += 1024) cnt[c * NB + i] = h[i];
}

// ---------------- pass 2a: per-bin exclusive scan over chunks ----------------
__global__ __launch_bounds__(256) void k_scan1(const int* __restrict__ cnt,
                                               int* __restrict__ cntOff,
                                               int* __restrict__ binTot) {
    __shared__ int s[256];
    int b = blockIdx.x, t = threadIdx.x;
    int x = cnt[t * NB + b];
    s[t] = x;
    __syncthreads();
    #pragma unroll
    for (int off = 1; off < 256; off <<= 1) {
        int v = (t >= off) ? s[t - off] : 0;
        __syncthreads();
        s[t] += v;
        __syncthreads();
    }
    cntOff[t * NB + b] = s[t] - x;
    if (t == 255) binTot[b] = s[255];
}

// ---------------- pass 2b: exclusive scan of bin totals ----------------
__global__ __launch_bounds__(256) void k_scan2(const int* __restrict__ binTot,
                                               int* __restrict__ binBase) {
    __shared__ int s[256];
    __shared__ int carry;
    int t = threadIdx.x;
    if (t == 0) carry = 0;
    __syncthreads();
    for (int base = 0; base < NB; base += 256) {
        int idx = base + t;
        int x = (idx < NB) ? binTot[idx] : 0;
        s[t] = x;
        __syncthreads();
        #pragma unroll
        for (int off = 1; off < 256; off <<= 1) {
            int v = (t >= off) ? s[t - off] : 0;
            __syncthreads();
            s[t] += v;
            __syncthreads();
        }
        if (idx < NB) binBase[idx] = carry + s[t] - x;
        __syncthreads();
        if (t == 255) carry += s[255];
        __syncthreads();
    }
    if (t == 0) binBase[NB] = carry;   // == NNZ
}

// ---------------- pass 3: scatter edges into bin-partitioned list (1024 threads) ----------------
__global__ __launch_bounds__(1024) void k_scatter(const int* __restrict__ rows,
                                                  const int* __restrict__ cols,
                                                  const float* __restrict__ vals,
                                                  const int* __restrict__ cntOff,
                                                  const int* __restrict__ binBase,
                                                  int2* __restrict__ eb) {
    __shared__ int cur[NB];
    int c = blockIdx.x, t = threadIdx.x;
    for (int i = t; i < NB; i += 1024) cur[i] = binBase[i] + cntOff[c * NB + i];
    __syncthreads();
    int end = (c + 1) * CHUNK;
    for (int e = c * CHUNK + t; e < end; e += 1024) {
        int r = rows[e];
        int b = r >> 7;
        int pos = atomicAdd(&cur[b], 1);
        eb[pos] = make_int2(cols[e] | ((r & 127) << 18), __float_as_int(vals[e]));
    }
}

// ---------------- pass 4: per-bin counting sort -> exact row-sorted CSR ----------------
__global__ __launch_bounds__(256) void k_binsort(const int2* __restrict__ eb,
                                                 const int* __restrict__ binBase,
                                                 int2* __restrict__ eb2,
                                                 int2* __restrict__ rowSC) {
    __shared__ int h[128];
    __shared__ int s[128];
    int b = blockIdx.x, t = threadIdx.x;
    if (t < 128) h[t] = 0;
    __syncthreads();
    int base = binBase[b];
    int cnt  = binBase[b + 1] - base;
    for (int j = t; j < cnt; j += 256)
        atomicAdd(&h[eb[base + j].x >> 18], 1);
    __syncthreads();
    if (t < 128) s[t] = h[t];
    __syncthreads();
    #pragma unroll
    for (int off = 1; off < 128; off <<= 1) {
        int v = 0;
        if (t < 128 && t >= off) v = s[t - off];
        __syncthreads();
        if (t < 128) s[t] += v;
        __syncthreads();
    }
    if (t < 128) {
        int e = s[t] - h[t];       // exclusive within-bin offset
        int r = (b << 7) + t;
        if (r < NTOT) rowSC[r] = make_int2(base + e, h[t]);
        s[t] = e;                  // becomes the cursor
    }
    __syncthreads();
    for (int j = t; j < cnt; j += 256) {
        int2 e = eb[base + j];
        int rl = e.x >> 18;
        int pos = base + atomicAdd(&s[rl], 1);
        eb2[pos] = make_int2(e.x & 0x3FFFF, e.y);
    }
}

// ---------------- SpMM layer: 16 lanes per row (4 rows/wave), 4-wide pipeline ----------------
__global__ __launch_bounds__(256) void k_spmm_row(const int2* __restrict__ rowSC,
                                                  const int2* __restrict__ eb2,
                                                  const unsigned short* __restrict__ embIn,
                                                  unsigned short* __restrict__ embOut) {
    int gt = blockIdx.x * 256 + threadIdx.x;
    int r  = gt >> 4;                 // row, one per 16-lane group
    if (r >= NTOT) return;
    int lq = threadIdx.x & 15;        // 4 dims per lane
    int2 sc = rowSC[r];
    int j = sc.x, end = sc.x + sc.y;
    float a0 = 0.f, a1 = 0.f, a2 = 0.f, a3 = 0.f;
    int doff = lq * 4;
    for (; j + 3 < end; j += 4) {
        int2 eA = eb2[j],     eB = eb2[j + 1];
        int2 eC = eb2[j + 2], eD = eb2[j + 3];
        uint2 mA = *(const uint2*)&embIn[eA.x * DL + doff];
        uint2 mB = *(const uint2*)&embIn[eB.x * DL + doff];
        uint2 mC = *(const uint2*)&embIn[eC.x * DL + doff];
        uint2 mD = *(const uint2*)&embIn[eD.x * DL + doff];
        float vA = __int_as_float(eA.y), vB = __int_as_float(eB.y);
        float vC = __int_as_float(eC.y), vD = __int_as_float(eD.y);
        a0 += vA * blo(mA.x); a1 += vA * bhi(mA.x); a2 += vA * blo(mA.y); a3 += vA * bhi(mA.y);
        a0 += vB * blo(mB.x); a1 += vB * bhi(mB.x); a2 += vB * blo(mB.y); a3 += vB * bhi(mB.y);
        a0 += vC * blo(mC.x); a1 += vC * bhi(mC.x); a2 += vC * blo(mC.y); a3 += vC * bhi(mC.y);
        a0 += vD * blo(mD.x); a1 += vD * bhi(mD.x); a2 += vD * blo(mD.y); a3 += vD * bhi(mD.y);
    }
    for (; j < end; ++j) {
        int2 e = eb2[j];
        uint2 m = *(const uint2*)&embIn[e.x * DL + doff];
        float v = __int_as_float(e.y);
        a0 += v * blo(m.x); a1 += v * bhi(m.x); a2 += v * blo(m.y); a3 += v * bhi(m.y);
    }
    uint2 o;
    o.x = pack2(a0, a1);
    o.y = pack2(a2, a3);
    *(uint2*)&embOut[r * DL + doff] = o;
}

// ---------------- last layer: same + fused out = 0.25*(e0+e1+e2+acc) ----------------
__global__ __launch_bounds__(256) void k_spmm_last(const int2* __restrict__ rowSC,
                                                   const int2* __restrict__ eb2,
                                                   const unsigned short* __restrict__ e0,
                                                   const unsigned short* __restrict__ e1,
                                                   const unsigned short* __restrict__ e2,
                                                   float* __restrict__ out) {
    int gt = blockIdx.x * 256 + threadIdx.x;
    int r  = gt >> 4;
    if (r >= NTOT) return;
    int lq = threadIdx.x & 15;
    int2 sc = rowSC[r];
    int j = sc.x, end = sc.x + sc.y;
    float a0 = 0.f, a1 = 0.f, a2 = 0.f, a3 = 0.f;
    int doff = lq * 4;
    for (; j + 3 < end; j += 4) {
        int2 eA = eb2[j],     eB = eb2[j + 1];
        int2 eC = eb2[j + 2], eD = eb2[j + 3];
        uint2 mA = *(const uint2*)&e2[eA.x * DL + doff];
        uint2 mB = *(const uint2*)&e2[eB.x * DL + doff];
        uint2 mC = *(const uint2*)&e2[eC.x * DL + doff];
        uint2 mD = *(const uint2*)&e2[eD.x * DL + doff];
        float vA = __int_as_float(eA.y), vB = __int_as_float(eB.y);
        float vC = __int_as_float(eC.y), vD = __int_as_float(eD.y);
        a0 += vA * blo(mA.x); a1 += vA * bhi(mA.x); a2 += vA * blo(mA.y); a3 += vA * bhi(mA.y);
        a0 += vB * blo(mB.x); a1 += vB * bhi(mB.x); a2 += vB * blo(mB.y); a3 += vB * bhi(mB.y);
        a0 += vC * blo(mC.x); a1 += vC * bhi(mC.x); a2 += vC * blo(mC.y); a3 += vC * bhi(mC.y);
        a0 += vD * blo(mD.x); a1 += vD * bhi(mD.x); a2 += vD * blo(mD.y); a3 += vD * bhi(mD.y);
    }
    for (; j < end; ++j) {
        int2 e = eb2[j];
        uint2 m = *(const uint2*)&e2[e.x * DL + doff];
        float v = __int_as_float(e.y);
        a0 += v * blo(m.x); a1 += v * bhi(m.x); a2 += v * blo(m.y); a3 += v * bhi(m.y);
    }
    int o = r * DL + doff;
    uint2 ua = *(const uint2*)&e0[o];
    uint2 ub = *(const uint2*)&e1[o];
    uint2 uc = *(const uint2*)&e2[o];
    float4 res;
    res.x = 0.25f * (blo(ua.x) + blo(ub.x) + blo(uc.x) + a0);
    res.y = 0.25f * (bhi(ua.x) + bhi(ub.x) + bhi(uc.x) + a1);
    res.z = 0.25f * (blo(ua.y) + blo(ub.y) + blo(uc.y) + a2);
    res.w = 0.25f * (bhi(ua.y) + bhi(ub.y) + bhi(uc.y) + a3);
    *(float4*)&out[o] = res;
}

extern "C" void kernel_launch(void* const* d_in, const int* in_sizes, int n_in,
                              void* d_out, int out_size, void* d_ws, size_t ws_size,
                              hipStream_t stream) {
    const float* F    = (const float*)d_in[0];
    const float* UP   = (const float*)d_in[1];
    const float* W    = (const float*)d_in[2];
    const float* B    = (const float*)d_in[3];
    const int*   rows = (const int*)d_in[4];
    const int*   cols = (const int*)d_in[5];
    const float* vals = (const float*)d_in[6];
    float* out = (float*)d_out;

    // workspace carve (~100 MB)
    unsigned short* e0 = (unsigned short*)d_ws;
    unsigned short* e1 = e0 + (size_t)NTOT * DL;
    unsigned short* e2 = e1 + (size_t)NTOT * DL;
    int2* eb      = (int2*)(e2 + (size_t)NTOT * DL);
    int2* eb2     = eb + (size_t)NNZ_;
    int2* rowSC   = eb2 + (size_t)NNZ_;
    int*  cnt     = (int*)(rowSC + NTOT);
    int*  cntOff  = cnt + (size_t)NCHUNK * NB;
    int*  binTot  = cntOff + (size_t)NCHUNK * NB;
    int*  binBase = binTot + NB;                      // NB+1 entries
    unsigned short* Wtb = (unsigned short*)(binBase + NB + 1);  // 64x512 bf16

    k_init<<<128 + (NUSER * DL) / 256, 256, 0, stream>>>(UP, W, e0, Wtb);
    k_item<<<(NITEM + 63) / 64, 256, 0, stream>>>(F, Wtb, B, e0);
    k_hist<<<NCHUNK, 1024, 0, stream>>>(rows, cnt);
    k_scan1<<<NB, 256, 0, stream>>>(cnt, cntOff, binTot);
    k_scan2<<<1, 256, 0, stream>>>(binTot, binBase);
    k_scatter<<<NCHUNK, 1024, 0, stream>>>(rows, cols, vals, cntOff, binBase, eb);
    k_binsort<<<NB, 256, 0, stream>>>(eb, binBase, eb2, rowSC);

    int spmm_blocks = (NTOT * 16 + 255) / 256;   // 16 threads per row
    k_spmm_row<<<spmm_blocks, 256, 0, stream>>>(rowSC, eb2, e0, e1);
    k_spmm_row<<<spmm_blocks, 256, 0, stream>>>(rowSC, eb2, e1, e2);
    k_spmm_last<<<spmm_blocks, 256, 0, stream>>>(rowSC, eb2, e0, e1, e2, out);
}

// Round 12
// 308.831 us; speedup vs baseline: 1.6823x; 1.0090x over previous
//
#include <hip/hip_runtime.h>

#define NUSER 100000
#define NITEM 50000
#define NTOT  150000
#define DF    512
#define DL    64
#define NNZ_  2400000
#define NB    1172        // ceil(150000/128) row-bins of 128 rows
#define NCHUNK 256
#define CHUNK  9375       // 256*9375 = 2,400,000 exactly

typedef short bf16x8 __attribute__((ext_vector_type(8)));
typedef float f32x4  __attribute__((ext_vector_type(4)));

__device__ __forceinline__ unsigned short bf16r(float f) {
    unsigned u = __float_as_uint(f);
    return (unsigned short)((u + 0x7FFFu + ((u >> 16) & 1u)) >> 16);
}
__device__ __forceinline__ unsigned pack2(float lo, float hi) {
    return (unsigned)bf16r(lo) | ((unsigned)bf16r(hi) << 16);
}
__device__ __forceinline__ float blo(unsigned u) { return __uint_as_float(u << 16); }
__device__ __forceinline__ float bhi(unsigned u) { return __uint_as_float(u & 0xFFFF0000u); }

// ---------------- init: W->Wtb bf16 transpose (blocks 0..127) + user normalize ----------------
__global__ __launch_bounds__(256) void k_init(const float* __restrict__ up,
                                              const float* __restrict__ W,
                                              unsigned short* __restrict__ e0,
                                              unsigned short* __restrict__ Wtb) {
    int b = blockIdx.x;
    if (b < 128) {
        int idx = b * 256 + threadIdx.x;    // 0..32767
        int k = idx >> 6, d = idx & 63;
        Wtb[d * DF + k] = bf16r(W[idx]);
        return;
    }
    int t = (b - 128) * 256 + threadIdx.x;
    float v = up[t];
    float ss = v * v;
    #pragma unroll
    for (int m = 32; m >= 1; m >>= 1) ss += __shfl_xor(ss, m, 64);
    float scale = 1.0f / fmaxf(sqrtf(ss), 1e-12f);
    e0[t] = bf16r(v * scale);
}

// ---------------- items: MFMA bf16 GEMM, K-split x4 (block = 16 rows, wave = K/4) ----------------
__global__ __launch_bounds__(256) void k_item(const float* __restrict__ F,
                                              const unsigned short* __restrict__ Wtb,
                                              const float* __restrict__ B,
                                              unsigned short* __restrict__ e0) {
    __shared__ float red[3][64][20];            // 15 KB; [20] pad: 16B-aligned, bank-spread
    int t = threadIdx.x;
    int w = t >> 6, lane = t & 63;
    int g = lane >> 4;          // k-subgroup 0..3
    int c = lane & 15;          // A-row / B-col index
    int row_base = blockIdx.x * 16;             // NITEM = 3125*16, no tail

    const float* Frow = F + (size_t)(row_base + c) * DF;
    int kbase = w * 128;                        // this wave's K-slice

    f32x4 acc[4] = {};                          // 4 col-tiles of 16x16
    #pragma unroll
    for (int kc = 0; kc < 128; kc += 32) {
        int k0 = kbase + kc + g * 8;
        float4 f0 = *(const float4*)&Frow[k0];
        float4 f1 = *(const float4*)&Frow[k0 + 4];
        union { uint4 u; bf16x8 v; } a;
        a.u.x = pack2(f0.x, f0.y);
        a.u.y = pack2(f0.z, f0.w);
        a.u.z = pack2(f1.x, f1.y);
        a.u.w = pack2(f1.z, f1.w);
        #pragma unroll
        for (int ct = 0; ct < 4; ++ct) {
            union { uint4 u; bf16x8 v; } bb;
            bb.u = *(const uint4*)&Wtb[(size_t)(ct * 16 + c) * DF + k0];
            acc[ct] = __builtin_amdgcn_mfma_f32_16x16x32_bf16(a.v, bb.v, acc[ct], 0, 0, 0);
        }
    }

    if (w > 0) {
        #pragma unroll
        for (int ct = 0; ct < 4; ++ct)
            *(f32x4*)&red[w - 1][lane][ct * 4] = acc[ct];
    }
    __syncthreads();
    if (w != 0) return;

    #pragma unroll
    for (int i = 0; i < 3; ++i) {
        #pragma unroll
        for (int ct = 0; ct < 4; ++ct) {
            f32x4 p = *(const f32x4*)&red[i][lane][ct * 4];
            acc[ct] += p;
        }
    }

    #pragma unroll
    for (int ct = 0; ct < 4; ++ct) {
        float bc = B[ct * 16 + c];
        #pragma unroll
        for (int r = 0; r < 4; ++r) acc[ct][r] += bc;
    }
    float ssv[4];
    #pragma unroll
    for (int r = 0; r < 4; ++r) {
        float s = acc[0][r] * acc[0][r] + acc[1][r] * acc[1][r]
                + acc[2][r] * acc[2][r] + acc[3][r] * acc[3][r];
        #pragma unroll
        for (int m = 1; m <= 8; m <<= 1) s += __shfl_xor(s, m, 64);
        ssv[r] = 1.0f / fmaxf(sqrtf(s), 1e-12f);
    }
    #pragma unroll
    for (int r = 0; r < 4; ++r) {
        int gr = row_base + g * 4 + r;
        size_t o = (size_t)(NUSER + gr) * DL + c;
        #pragma unroll
        for (int ct = 0; ct < 4; ++ct)
            e0[o + ct * 16] = bf16r(acc[ct][r] * ssv[r]);
    }
}

// ---------------- pass 1: per-chunk histogram over row-bins (1024 threads) ----------------
__global__ __launch_bounds__(1024) void k_hist(const int* __restrict__ rows,
                                               int* __restrict__ cnt) {
    __shared__ int h[NB];
    int c = blockIdx.x, t = threadIdx.x;
    for (int i = t; i < NB; i += 1024) h[i] = 0;
    __syncthreads();
    int end = (c + 1) * CHUNK;
    for (int e = c * CHUNK + t; e < end; e += 1024)
        atomicAdd(&h[rows[e] >> 7], 1);
    __syncthreads();
    for (int i = t; i < NB; i += 1024) cnt[c * NB + i] = h[i];
}

// ---------------- pass 2a: per-bin exclusive scan over chunks ----------------
__global__ __launch_bounds__(256) void k_scan1(const int* __restrict__ cnt,
                                               int* __restrict__ cntOff,
                                               int* __restrict__ binTot) {
    __shared__ int s[256];
    int b = blockIdx.x, t = threadIdx.x;
    int x = cnt[t * NB + b];
    s[t] = x;
    __syncthreads();
    #pragma unroll
    for (int off = 1; off < 256; off <<= 1) {
        int v = (t >= off) ? s[t - off] : 0;
        __syncthreads();
        s[t] += v;
        __syncthreads();
    }
    cntOff[t * NB + b] = s[t] - x;
    if (t == 255) binTot[b] = s[255];
}

// ---------------- pass 2b: exclusive scan of bin totals ----------------
__global__ __launch_bounds__(256) void k_scan2(const int* __restrict__ binTot,
                                               int* __restrict__ binBase) {
    __shared__ int s[256];
    __shared__ int carry;
    int t = threadIdx.x;
    if (t == 0) carry = 0;
    __syncthreads();
    for (int base = 0; base < NB; base += 256) {
        int idx = base + t;
        int x = (idx < NB) ? binTot[idx] : 0;
        s[t] = x;
        __syncthreads();
        #pragma unroll
        for (int off = 1; off < 256; off <<= 1) {
            int v = (t >= off) ? s[t - off] : 0;
            __syncthreads();
            s[t] += v;
            __syncthreads();
        }
        if (idx < NB) binBase[idx] = carry + s[t] - x;
        __syncthreads();
        if (t == 255) carry += s[255];
        __syncthreads();
    }
    if (t == 0) binBase[NB] = carry;   // == NNZ
}

// ---------------- pass 3: scatter edges into bin-partitioned list (1024 threads) ----------------
__global__ __launch_bounds__(1024) void k_scatter(const int* __restrict__ rows,
                                                  const int* __restrict__ cols,
                                                  const float* __restrict__ vals,
                                                  const int* __restrict__ cntOff,
                                                  const int* __restrict__ binBase,
                                                  int2* __restrict__ eb) {
    __shared__ int cur[NB];
    int c = blockIdx.x, t = threadIdx.x;
    for (int i = t; i < NB; i += 1024) cur[i] = binBase[i] + cntOff[c * NB + i];
    __syncthreads();
    int end = (c + 1) * CHUNK;
    for (int e = c * CHUNK + t; e < end; e += 1024) {
        int r = rows[e];
        int b = r >> 7;
        int pos = atomicAdd(&cur[b], 1);
        eb[pos] = make_int2(cols[e] | ((r & 127) << 18), __float_as_int(vals[e]));
    }
}

// ---------------- pass 4: per-bin counting sort -> exact row-sorted CSR ----------------
__global__ __launch_bounds__(256) void k_binsort(const int2* __restrict__ eb,
                                                 const int* __restrict__ binBase,
                                                 int2* __restrict__ eb2,
                                                 int2* __restrict__ rowSC) {
    __shared__ int h[128];
    __shared__ int s[128];
    int b = blockIdx.x, t = threadIdx.x;
    if (t < 128) h[t] = 0;
    __syncthreads();
    int base = binBase[b];
    int cnt  = binBase[b + 1] - base;
    for (int j = t; j < cnt; j += 256)
        atomicAdd(&h[eb[base + j].x >> 18], 1);
    __syncthreads();
    if (t < 128) s[t] = h[t];
    __syncthreads();
    #pragma unroll
    for (int off = 1; off < 128; off <<= 1) {
        int v = 0;
        if (t < 128 && t >= off) v = s[t - off];
        __syncthreads();
        if (t < 128) s[t] += v;
        __syncthreads();
    }
    if (t < 128) {
        int e = s[t] - h[t];       // exclusive within-bin offset
        int r = (b << 7) + t;
        if (r < NTOT) rowSC[r] = make_int2(base + e, h[t]);
        s[t] = e;                  // becomes the cursor
    }
    __syncthreads();
    for (int j = t; j < cnt; j += 256) {
        int2 e = eb[base + j];
        int rl = e.x >> 18;
        int pos = base + atomicAdd(&s[rl], 1);
        eb2[pos] = make_int2(e.x & 0x3FFFF, e.y);
    }
}

// ---------------- SpMM layer: 16 lanes per row (4 rows/wave), 4-wide pipeline ----------------
__global__ __launch_bounds__(256) void k_spmm_row(const int2* __restrict__ rowSC,
                                                  const int2* __restrict__ eb2,
                                                  const unsigned short* __restrict__ embIn,
                                                  unsigned short* __restrict__ embOut) {
    int gt = blockIdx.x * 256 + threadIdx.x;
    int r  = gt >> 4;                 // row, one per 16-lane group
    if (r >= NTOT) return;
    int lq = threadIdx.x & 15;        // 4 dims per lane
    int2 sc = rowSC[r];
    int j = sc.x, end = sc.x + sc.y;
    float a0 = 0.f, a1 = 0.f, a2 = 0.f, a3 = 0.f;
    int doff = lq * 4;
    for (; j + 3 < end; j += 4) {
        int2 eA = eb2[j],     eB = eb2[j + 1];
        int2 eC = eb2[j + 2], eD = eb2[j + 3];
        uint2 mA = *(const uint2*)&embIn[eA.x * DL + doff];
        uint2 mB = *(const uint2*)&embIn[eB.x * DL + doff];
        uint2 mC = *(const uint2*)&embIn[eC.x * DL + doff];
        uint2 mD = *(const uint2*)&embIn[eD.x * DL + doff];
        float vA = __int_as_float(eA.y), vB = __int_as_float(eB.y);
        float vC = __int_as_float(eC.y), vD = __int_as_float(eD.y);
        a0 += vA * blo(mA.x); a1 += vA * bhi(mA.x); a2 += vA * blo(mA.y); a3 += vA * bhi(mA.y);
        a0 += vB * blo(mB.x); a1 += vB * bhi(mB.x); a2 += vB * blo(mB.y); a3 += vB * bhi(mB.y);
        a0 += vC * blo(mC.x); a1 += vC * bhi(mC.x); a2 += vC * blo(mC.y); a3 += vC * bhi(mC.y);
        a0 += vD * blo(mD.x); a1 += vD * bhi(mD.x); a2 += vD * blo(mD.y); a3 += vD * bhi(mD.y);
    }
    for (; j < end; ++j) {
        int2 e = eb2[j];
        uint2 m = *(const uint2*)&embIn[e.x * DL + doff];
        float v = __int_as_float(e.y);
        a0 += v * blo(m.x); a1 += v * bhi(m.x); a2 += v * blo(m.y); a3 += v * bhi(m.y);
    }
    uint2 o;
    o.x = pack2(a0, a1);
    o.y = pack2(a2, a3);
    *(uint2*)&embOut[r * DL + doff] = o;
}

// ---------------- last layer: same + fused out = 0.25*(e0+e1+e2+acc) ----------------
__global__ __launch_bounds__(256) void k_spmm_last(const int2* __restrict__ rowSC,
                                                   const int2* __restrict__ eb2,
                                                   const unsigned short* __restrict__ e0,
                                                   const unsigned short* __restrict__ e1,
                                                   const unsigned short* __restrict__ e2,
                                                   float* __restrict__ out) {
    int gt = blockIdx.x * 256 + threadIdx.x;
    int r  = gt >> 4;
    if (r >= NTOT) return;
    int lq = threadIdx.x & 15;
    int2 sc = rowSC[r];
    int j = sc.x, end = sc.x + sc.y;
    float a0 = 0.f, a1 = 0.f, a2 = 0.f, a3 = 0.f;
    int doff = lq * 4;
    for (; j + 3 < end; j += 4) {
        int2 eA = eb2[j],     eB = eb2[j + 1];
        int2 eC = eb2[j + 2], eD = eb2[j + 3];
        uint2 mA = *(const uint2*)&e2[eA.x * DL + doff];
        uint2 mB = *(const uint2*)&e2[eB.x * DL + doff];
        uint2 mC = *(const uint2*)&e2[eC.x * DL + doff];
        uint2 mD = *(const uint2*)&e2[eD.x * DL + doff];
        float vA = __int_as_float(eA.y), vB = __int_as_float(eB.y);
        float vC = __int_as_float(eC.y), vD = __int_as_float(eD.y);
        a0 += vA * blo(mA.x); a1 += vA * bhi(mA.x); a2 += vA * blo(mA.y); a3 += vA * bhi(mA.y);
        a0 += vB * blo(mB.x); a1 += vB * bhi(mB.x); a2 += vB * blo(mB.y); a3 += vB * bhi(mB.y);
        a0 += vC * blo(mC.x); a1 += vC * bhi(mC.x); a2 += vC * blo(mC.y); a3 += vC * bhi(mC.y);
        a0 += vD * blo(mD.x); a1 += vD * bhi(mD.x); a2 += vD * blo(mD.y); a3 += vD * bhi(mD.y);
    }
    for (; j < end; ++j) {
        int2 e = eb2[j];
        uint2 m = *(const uint2*)&e2[e.x * DL + doff];
        float v = __int_as_float(e.y);
        a0 += v * blo(m.x); a1 += v * bhi(m.x); a2 += v * blo(m.y); a3 += v * bhi(m.y);
    }
    int o = r * DL + doff;
    uint2 ua = *(const uint2*)&e0[o];
    uint2 ub = *(const uint2*)&e1[o];
    uint2 uc = *(const uint2*)&e2[o];
    float4 res;
    res.x = 0.25f * (blo(ua.x) + blo(ub.x) + blo(uc.x) + a0);
    res.y = 0.25f * (bhi(ua.x) + bhi(ub.x) + bhi(uc.x) + a1);
    res.z = 0.25f * (blo(ua.y) + blo(ub.y) + blo(uc.y) + a2);
    res.w = 0.25f * (bhi(ua.y) + bhi(ub.y) + bhi(uc.y) + a3);
    *(float4*)&out[o] = res;
}

extern "C" void kernel_launch(void* const* d_in, const int* in_sizes, int n_in,
                              void* d_out, int out_size, void* d_ws, size_t ws_size,
                              hipStream_t stream) {
    const float* F    = (const float*)d_in[0];
    const float* UP   = (const float*)d_in[1];
    const float* W    = (const float*)d_in[2];
    const float* B    = (const float*)d_in[3];
    const int*   rows = (const int*)d_in[4];
    const int*   cols = (const int*)d_in[5];
    const float* vals = (const float*)d_in[6];
    float* out = (float*)d_out;

    // workspace carve (~100 MB)
    unsigned short* e0 = (unsigned short*)d_ws;
    unsigned short* e1 = e0 + (size_t)NTOT * DL;
    unsigned short* e2 = e1 + (size_t)NTOT * DL;
    int2* eb      = (int2*)(e2 + (size_t)NTOT * DL);
    int2* eb2     = eb + (size_t)NNZ_;
    int2* rowSC   = eb2 + (size_t)NNZ_;
    int*  cnt     = (int*)(rowSC + NTOT);
    int*  cntOff  = cnt + (size_t)NCHUNK * NB;
    int*  binTot  = cntOff + (size_t)NCHUNK * NB;
    int*  binBase = binTot + NB;                      // NB+1 entries
    unsigned short* Wtb = (unsigned short*)(binBase + NB + 1);  // 64x512 bf16

    k_init<<<128 + (NUSER * DL) / 256, 256, 0, stream>>>(UP, W, e0, Wtb);
    k_item<<<NITEM / 16, 256, 0, stream>>>(F, Wtb, B, e0);
    k_hist<<<NCHUNK, 1024, 0, stream>>>(rows, cnt);
    k_scan1<<<NB, 256, 0, stream>>>(cnt, cntOff, binTot);
    k_scan2<<<1, 256, 0, stream>>>(binTot, binBase);
    k_scatter<<<NCHUNK, 1024, 0, stream>>>(rows, cols, vals, cntOff, binBase, eb);
    k_binsort<<<NB, 256, 0, stream>>>(eb, binBase, eb2, rowSC);

    int spmm_blocks = (NTOT * 16 + 255) / 256;   // 16 threads per row
    k_spmm_row<<<spmm_blocks, 256, 0, stream>>>(rowSC, eb2, e0, e1);
    k_spmm_row<<<spmm_blocks, 256, 0, stream>>>(rowSC, eb2, e1, e2);
    k_spmm_last<<<spmm_blocks, 256, 0, stream>>>(rowSC, eb2, e0, e1, e2, out);
}

// Round 13
// 287.953 us; speedup vs baseline: 1.8042x; 1.0725x over previous
//
#include <hip/hip_runtime.h>

#define NUSER 100000
#define NITEM 50000
#define NTOT  150000
#define DF    512
#define DL    64
#define NNZ_  2400000
#define NB    1172        // ceil(150000/128) row-bins of 128 rows
#define NCHUNK 256
#define CHUNK  9375       // 256*9375 = 2,400,000 exactly

typedef short bf16x8 __attribute__((ext_vector_type(8)));
typedef float f32x4  __attribute__((ext_vector_type(4)));

__device__ __forceinline__ unsigned short bf16r(float f) {
    unsigned u = __float_as_uint(f);
    return (unsigned short)((u + 0x7FFFu + ((u >> 16) & 1u)) >> 16);
}
__device__ __forceinline__ unsigned pack2(float lo, float hi) {
    return (unsigned)bf16r(lo) | ((unsigned)bf16r(hi) << 16);
}
__device__ __forceinline__ float blo(unsigned u) { return __uint_as_float(u << 16); }
__device__ __forceinline__ float bhi(unsigned u) { return __uint_as_float(u & 0xFFFF0000u); }

// ---------------- init: W->Wtb bf16 transpose (blocks 0..127) + user normalize ----------------
__global__ __launch_bounds__(256) void k_init(const float* __restrict__ up,
                                              const float* __restrict__ W,
                                              unsigned short* __restrict__ e0,
                                              unsigned short* __restrict__ Wtb) {
    int b = blockIdx.x;
    if (b < 128) {
        int idx = b * 256 + threadIdx.x;    // 0..32767
        int k = idx >> 6, d = idx & 63;
        Wtb[d * DF + k] = bf16r(W[idx]);
        return;
    }
    int t = (b - 128) * 256 + threadIdx.x;
    float v = up[t];
    float ss = v * v;
    #pragma unroll
    for (int m = 32; m >= 1; m >>= 1) ss += __shfl_xor(ss, m, 64);
    float scale = 1.0f / fmaxf(sqrtf(ss), 1e-12f);
    e0[t] = bf16r(v * scale);
}

// ---------------- items: MFMA bf16 GEMM, LDS-staged 64-row tile ----------------
#define KC 64
__global__ __launch_bounds__(256) void k_item(const float* __restrict__ F,
                                              const unsigned short* __restrict__ Wtb,
                                              const float* __restrict__ B,
                                              unsigned short* __restrict__ e0) {
    __shared__ unsigned short fa[64][72];   // F tile bf16, pad 72 -> 2-way-max bank alias
    __shared__ unsigned short wb[64][72];   // W chunk bf16 [col][k]
    int t = threadIdx.x;
    int w = t >> 6, lane = t & 63;
    int g = lane >> 4;          // k-subgroup 0..3
    int c = lane & 15;          // A-row / B-col index within tile
    int row0 = blockIdx.x * 64;

    f32x4 acc[4] = {};          // 4 col-tiles of 16x16, full K accumulated per wave
    for (int kc = 0; kc < DF; kc += KC) {
        // stage F tile: 64 rows x 64 k; convert fp32->bf16 in flight (512 items, 2/thread)
        #pragma unroll
        for (int i = 0; i < 2; ++i) {
            int li = t + i * 256;
            int r = li >> 3, k8 = (li & 7) * 8;      // 8 lanes/row, 32B per lane
            int gr = row0 + r;
            if (gr >= NITEM) gr = NITEM - 1;         // clamp; stores guarded
            const float* p = &F[(size_t)gr * DF + kc + k8];
            float4 f0 = *(const float4*)p;
            float4 f1 = *(const float4*)(p + 4);
            uint4 u;
            u.x = pack2(f0.x, f0.y); u.y = pack2(f0.z, f0.w);
            u.z = pack2(f1.x, f1.y); u.w = pack2(f1.z, f1.w);
            *(uint4*)&fa[r][k8] = u;
        }
        // stage W chunk: 64 cols x 64 k (bf16 already)
        #pragma unroll
        for (int i = 0; i < 2; ++i) {
            int li = t + i * 256;
            int d = li >> 3, k8 = (li & 7) * 8;
            *(uint4*)&wb[d][k8] = *(const uint4*)&Wtb[(size_t)d * DF + kc + k8];
        }
        __syncthreads();
        #pragma unroll
        for (int k2 = 0; k2 < KC; k2 += 32) {
            union { uint4 u; bf16x8 v; } a;
            a.u = *(const uint4*)&fa[w * 16 + c][k2 + g * 8];
            #pragma unroll
            for (int ct = 0; ct < 4; ++ct) {
                union { uint4 u; bf16x8 v; } bb;
                bb.u = *(const uint4*)&wb[ct * 16 + c][k2 + g * 8];
                acc[ct] = __builtin_amdgcn_mfma_f32_16x16x32_bf16(a.v, bb.v, acc[ct], 0, 0, 0);
            }
        }
        __syncthreads();
    }

    int row_base = row0 + w * 16;
    #pragma unroll
    for (int ct = 0; ct < 4; ++ct) {
        float bc = B[ct * 16 + c];
        #pragma unroll
        for (int r = 0; r < 4; ++r) acc[ct][r] += bc;
    }
    float ssv[4];
    #pragma unroll
    for (int r = 0; r < 4; ++r) {
        float s = acc[0][r] * acc[0][r] + acc[1][r] * acc[1][r]
                + acc[2][r] * acc[2][r] + acc[3][r] * acc[3][r];
        #pragma unroll
        for (int m = 1; m <= 8; m <<= 1) s += __shfl_xor(s, m, 64);  // over 16 cols, row-invariant
        ssv[r] = 1.0f / fmaxf(sqrtf(s), 1e-12f);
    }
    #pragma unroll
    for (int r = 0; r < 4; ++r) {
        int gr = row_base + g * 4 + r;
        if (gr < NITEM) {
            size_t o = (size_t)(NUSER + gr) * DL + c;
            #pragma unroll
            for (int ct = 0; ct < 4; ++ct)
                e0[o + ct * 16] = bf16r(acc[ct][r] * ssv[r]);
        }
    }
}

// ---------------- pass 1: per-chunk histogram over row-bins (1024 threads) ----------------
__global__ __launch_bounds__(1024) void k_hist(const int* __restrict__ rows,
                                               int* __restrict__ cnt) {
    __shared__ int h[NB];
    int c = blockIdx.x, t = threadIdx.x;
    for (int i = t; i < NB; i += 1024) h[i] = 0;
    __syncthreads();
    int end = (c + 1) * CHUNK;
    for (int e = c * CHUNK + t; e < end; e += 1024)
        atomicAdd(&h[rows[e] >> 7], 1);
    __syncthreads();
    for (int i = t; i < NB; i += 1024) cnt[c * NB + i] = h[i];
}

// ---------------- pass 2a: per-bin exclusive scan over chunks ----------------
__global__ __launch_bounds__(256) void k_scan1(const int* __restrict__ cnt,
                                               int* __restrict__ cntOff,
                                               int* __restrict__ binTot) {
    __shared__ int s[256];
    int b = blockIdx.x, t = threadIdx.x;
    int x = cnt[t * NB + b];
    s[t] = x;
    __syncthreads();
    #pragma unroll
    for (int off = 1; off < 256; off <<= 1) {
        int v = (t >= off) ? s[t - off] : 0;
        __syncthreads();
        s[t] += v;
        __syncthreads();
    }
    cntOff[t * NB + b] = s[t] - x;
    if (t == 255) binTot[b] = s[255];
}

// ---------------- pass 2b: exclusive scan of bin totals ----------------
__global__ __launch_bounds__(256) void k_scan2(const int* __restrict__ binTot,
                                               int* __restrict__ binBase) {
    __shared__ int s[256];
    __shared__ int carry;
    int t = threadIdx.x;
    if (t == 0) carry = 0;
    __syncthreads();
    for (int base = 0; base < NB; base += 256) {
        int idx = base + t;
        int x = (idx < NB) ? binTot[idx] : 0;
        s[t] = x;
        __syncthreads();
        #pragma unroll
        for (int off = 1; off < 256; off <<= 1) {
            int v = (t >= off) ? s[t - off] : 0;
            __syncthreads();
            s[t] += v;
            __syncthreads();
        }
        if (idx < NB) binBase[idx] = carry + s[t] - x;
        __syncthreads();
        if (t == 255) carry += s[255];
        __syncthreads();
    }
    if (t == 0) binBase[NB] = carry;   // == NNZ
}

// ---------------- pass 3: scatter edges into bin-partitioned list (1024 threads) ----------------
__global__ __launch_bounds__(1024) void k_scatter(const int* __restrict__ rows,
                                                  const int* __restrict__ cols,
                                                  const float* __restrict__ vals,
                                                  const int* __restrict__ cntOff,
                                                  const int* __restrict__ binBase,
                                                  int2* __restrict__ eb) {
    __shared__ int cur[NB];
    int c = blockIdx.x, t = threadIdx.x;
    for (int i = t; i < NB; i += 1024) cur[i] = binBase[i] + cntOff[c * NB + i];
    __syncthreads();
    int end = (c + 1) * CHUNK;
    for (int e = c * CHUNK + t; e < end; e += 1024) {
        int r = rows[e];
        int b = r >> 7;
        int pos = atomicAdd(&cur[b], 1);
        eb[pos] = make_int2(cols[e] | ((r & 127) << 18), __float_as_int(vals[e]));
    }
}

// ---------------- pass 4: per-bin counting sort -> exact row-sorted CSR ----------------
__global__ __launch_bounds__(256) void k_binsort(const int2* __restrict__ eb,
                                                 const int* __restrict__ binBase,
                                                 int2* __restrict__ eb2,
                                                 int2* __restrict__ rowSC) {
    __shared__ int h[128];
    __shared__ int s[128];
    int b = blockIdx.x, t = threadIdx.x;
    if (t < 128) h[t] = 0;
    __syncthreads();
    int base = binBase[b];
    int cnt  = binBase[b + 1] - base;
    for (int j = t; j < cnt; j += 256)
        atomicAdd(&h[eb[base + j].x >> 18], 1);
    __syncthreads();
    if (t < 128) s[t] = h[t];
    __syncthreads();
    #pragma unroll
    for (int off = 1; off < 128; off <<= 1) {
        int v = 0;
        if (t < 128 && t >= off) v = s[t - off];
        __syncthreads();
        if (t < 128) s[t] += v;
        __syncthreads();
    }
    if (t < 128) {
        int e = s[t] - h[t];       // exclusive within-bin offset
        int r = (b << 7) + t;
        if (r < NTOT) rowSC[r] = make_int2(base + e, h[t]);
        s[t] = e;                  // becomes the cursor
    }
    __syncthreads();
    for (int j = t; j < cnt; j += 256) {
        int2 e = eb[base + j];
        int rl = e.x >> 18;
        int pos = base + atomicAdd(&s[rl], 1);
        eb2[pos] = make_int2(e.x & 0x3FFFF, e.y);
    }
}

// ---------------- SpMM layer: 16 lanes per row (4 rows/wave), 4-wide pipeline ----------------
__global__ __launch_bounds__(256) void k_spmm_row(const int2* __restrict__ rowSC,
                                                  const int2* __restrict__ eb2,
                                                  const unsigned short* __restrict__ embIn,
                                                  unsigned short* __restrict__ embOut) {
    int gt = blockIdx.x * 256 + threadIdx.x;
    int r  = gt >> 4;                 // row, one per 16-lane group
    if (r >= NTOT) return;
    int lq = threadIdx.x & 15;        // 4 dims per lane
    int2 sc = rowSC[r];
    int j = sc.x, end = sc.x + sc.y;
    float a0 = 0.f, a1 = 0.f, a2 = 0.f, a3 = 0.f;
    int doff = lq * 4;
    for (; j + 3 < end; j += 4) {
        int2 eA = eb2[j],     eB = eb2[j + 1];
        int2 eC = eb2[j + 2], eD = eb2[j + 3];
        uint2 mA = *(const uint2*)&embIn[eA.x * DL + doff];
        uint2 mB = *(const uint2*)&embIn[eB.x * DL + doff];
        uint2 mC = *(const uint2*)&embIn[eC.x * DL + doff];
        uint2 mD = *(const uint2*)&embIn[eD.x * DL + doff];
        float vA = __int_as_float(eA.y), vB = __int_as_float(eB.y);
        float vC = __int_as_float(eC.y), vD = __int_as_float(eD.y);
        a0 += vA * blo(mA.x); a1 += vA * bhi(mA.x); a2 += vA * blo(mA.y); a3 += vA * bhi(mA.y);
        a0 += vB * blo(mB.x); a1 += vB * bhi(mB.x); a2 += vB * blo(mB.y); a3 += vB * bhi(mB.y);
        a0 += vC * blo(mC.x); a1 += vC * bhi(mC.x); a2 += vC * blo(mC.y); a3 += vC * bhi(mC.y);
        a0 += vD * blo(mD.x); a1 += vD * bhi(mD.x); a2 += vD * blo(mD.y); a3 += vD * bhi(mD.y);
    }
    for (; j < end; ++j) {
        int2 e = eb2[j];
        uint2 m = *(const uint2*)&embIn[e.x * DL + doff];
        float v = __int_as_float(e.y);
        a0 += v * blo(m.x); a1 += v * bhi(m.x); a2 += v * blo(m.y); a3 += v * bhi(m.y);
    }
    uint2 o;
    o.x = pack2(a0, a1);
    o.y = pack2(a2, a3);
    *(uint2*)&embOut[r * DL + doff] = o;
}

// ---------------- last layer: same + fused out = 0.25*(e0+e1+e2+acc) ----------------
__global__ __launch_bounds__(256) void k_spmm_last(const int2* __restrict__ rowSC,
                                                   const int2* __restrict__ eb2,
                                                   const unsigned short* __restrict__ e0,
                                                   const unsigned short* __restrict__ e1,
                                                   const unsigned short* __restrict__ e2,
                                                   float* __restrict__ out) {
    int gt = blockIdx.x * 256 + threadIdx.x;
    int r  = gt >> 4;
    if (r >= NTOT) return;
    int lq = threadIdx.x & 15;
    int2 sc = rowSC[r];
    int j = sc.x, end = sc.x + sc.y;
    float a0 = 0.f, a1 = 0.f, a2 = 0.f, a3 = 0.f;
    int doff = lq * 4;
    for (; j + 3 < end; j += 4) {
        int2 eA = eb2[j],     eB = eb2[j + 1];
        int2 eC = eb2[j + 2], eD = eb2[j + 3];
        uint2 mA = *(const uint2*)&e2[eA.x * DL + doff];
        uint2 mB = *(const uint2*)&e2[eB.x * DL + doff];
        uint2 mC = *(const uint2*)&e2[eC.x * DL + doff];
        uint2 mD = *(const uint2*)&e2[eD.x * DL + doff];
        float vA = __int_as_float(eA.y), vB = __int_as_float(eB.y);
        float vC = __int_as_float(eC.y), vD = __int_as_float(eD.y);
        a0 += vA * blo(mA.x); a1 += vA * bhi(mA.x); a2 += vA * blo(mA.y); a3 += vA * bhi(mA.y);
        a0 += vB * blo(mB.x); a1 += vB * bhi(mB.x); a2 += vB * blo(mB.y); a3 += vB * bhi(mB.y);
        a0 += vC * blo(mC.x); a1 += vC * bhi(mC.x); a2 += vC * blo(mC.y); a3 += vC * bhi(mC.y);
        a0 += vD * blo(mD.x); a1 += vD * bhi(mD.x); a2 += vD * blo(mD.y); a3 += vD * bhi(mD.y);
    }
    for (; j < end; ++j) {
        int2 e = eb2[j];
        uint2 m = *(const uint2*)&e2[e.x * DL + doff];
        float v = __int_as_float(e.y);
        a0 += v * blo(m.x); a1 += v * bhi(m.x); a2 += v * blo(m.y); a3 += v * bhi(m.y);
    }
    int o = r * DL + doff;
    uint2 ua = *(const uint2*)&e0[o];
    uint2 ub = *(const uint2*)&e1[o];
    uint2 uc = *(const uint2*)&e2[o];
    float4 res;
    res.x = 0.25f * (blo(ua.x) + blo(ub.x) + blo(uc.x) + a0);
    res.y = 0.25f * (bhi(ua.x) + bhi(ub.x) + bhi(uc.x) + a1);
    res.z = 0.25f * (blo(ua.y) + blo(ub.y) + blo(uc.y) + a2);
    res.w = 0.25f * (bhi(ua.y) + bhi(ub.y) + bhi(uc.y) + a3);
    *(float4*)&out[o] = res;
}

extern "C" void kernel_launch(void* const* d_in, const int* in_sizes, int n_in,
                              void* d_out, int out_size, void* d_ws, size_t ws_size,
                              hipStream_t stream) {
    const float* F    = (const float*)d_in[0];
    const float* UP   = (const float*)d_in[1];
    const float* W    = (const float*)d_in[2];
    const float* B    = (const float*)d_in[3];
    const int*   rows = (const int*)d_in[4];
    const int*   cols = (const int*)d_in[5];
    const float* vals = (const float*)d_in[6];
    float* out = (float*)d_out;

    // workspace carve (~100 MB)
    unsigned short* e0 = (unsigned short*)d_ws;
    unsigned short* e1 = e0 + (size_t)NTOT * DL;
    unsigned short* e2 = e1 + (size_t)NTOT * DL;
    int2* eb      = (int2*)(e2 + (size_t)NTOT * DL);
    int2* eb2     = eb + (size_t)NNZ_;
    int2* rowSC   = eb2 + (size_t)NNZ_;
    int*  cnt     = (int*)(rowSC + NTOT);
    int*  cntOff  = cnt + (size_t)NCHUNK * NB;
    int*  binTot  = cntOff + (size_t)NCHUNK * NB;
    int*  binBase = binTot + NB;                      // NB+1 entries
    unsigned short* Wtb = (unsigned short*)(binBase + NB + 1);  // 64x512 bf16

    k_init<<<128 + (NUSER * DL) / 256, 256, 0, stream>>>(UP, W, e0, Wtb);
    k_item<<<(NITEM + 63) / 64, 256, 0, stream>>>(F, Wtb, B, e0);
    k_hist<<<NCHUNK, 1024, 0, stream>>>(rows, cnt);
    k_scan1<<<NB, 256, 0, stream>>>(cnt, cntOff, binTot);
    k_scan2<<<1, 256, 0, stream>>>(binTot, binBase);
    k_scatter<<<NCHUNK, 1024, 0, stream>>>(rows, cols, vals, cntOff, binBase, eb);
    k_binsort<<<NB, 256, 0, stream>>>(eb, binBase, eb2, rowSC);

    int spmm_blocks = (NTOT * 16 + 255) / 256;   // 16 threads per row
    k_spmm_row<<<spmm_blocks, 256, 0, stream>>>(rowSC, eb2, e0, e1);
    k_spmm_row<<<spmm_blocks, 256, 0, stream>>>(rowSC, eb2, e1, e2);
    k_spmm_last<<<spmm_blocks, 256, 0, stream>>>(rowSC, eb2, e0, e1, e2, out);
}

// Round 14
// 286.900 us; speedup vs baseline: 1.8109x; 1.0037x over previous
//
#include <hip/hip_runtime.h>

#define NUSER 100000
#define NITEM 50000
#define NTOT  150000
#define DF    512
#define DL    64
#define NNZ_  2400000
#define NB    1172        // ceil(150000/128) row-bins of 128 rows
#define NCHUNK 256
#define CHUNK  9375       // 256*9375 = 2,400,000 exactly

typedef short bf16x8 __attribute__((ext_vector_type(8)));
typedef float f32x4  __attribute__((ext_vector_type(4)));

__device__ __forceinline__ unsigned short bf16r(float f) {
    unsigned u = __float_as_uint(f);
    return (unsigned short)((u + 0x7FFFu + ((u >> 16) & 1u)) >> 16);
}
__device__ __forceinline__ unsigned pack2(float lo, float hi) {
    return (unsigned)bf16r(lo) | ((unsigned)bf16r(hi) << 16);
}
__device__ __forceinline__ float blo(unsigned u) { return __uint_as_float(u << 16); }
__device__ __forceinline__ float bhi(unsigned u) { return __uint_as_float(u & 0xFFFF0000u); }

// ---------------- init: W->Wtb bf16 transpose (blocks 0..127) + user normalize ----------------
__global__ __launch_bounds__(256) void k_init(const float* __restrict__ up,
                                              const float* __restrict__ W,
                                              unsigned short* __restrict__ e0,
                                              unsigned short* __restrict__ Wtb) {
    int b = blockIdx.x;
    if (b < 128) {
        int idx = b * 256 + threadIdx.x;    // 0..32767
        int k = idx >> 6, d = idx & 63;
        Wtb[d * DF + k] = bf16r(W[idx]);
        return;
    }
    int t = (b - 128) * 256 + threadIdx.x;
    float v = up[t];
    float ss = v * v;
    #pragma unroll
    for (int m = 32; m >= 1; m >>= 1) ss += __shfl_xor(ss, m, 64);
    float scale = 1.0f / fmaxf(sqrtf(ss), 1e-12f);
    e0[t] = bf16r(v * scale);
}

// ---------------- items: MFMA bf16 GEMM, LDS-staged 64-row tile ----------------
#define KC 64
__global__ __launch_bounds__(256) void k_item(const float* __restrict__ F,
                                              const unsigned short* __restrict__ Wtb,
                                              const float* __restrict__ B,
                                              unsigned short* __restrict__ e0) {
    __shared__ unsigned short fa[64][72];   // F tile bf16, pad 72 -> 2-way-max bank alias
    __shared__ unsigned short wb[64][72];   // W chunk bf16 [col][k]
    int t = threadIdx.x;
    int w = t >> 6, lane = t & 63;
    int g = lane >> 4;          // k-subgroup 0..3
    int c = lane & 15;          // A-row / B-col index within tile
    int row0 = blockIdx.x * 64;

    f32x4 acc[4] = {};          // 4 col-tiles of 16x16, full K accumulated per wave
    for (int kc = 0; kc < DF; kc += KC) {
        #pragma unroll
        for (int i = 0; i < 2; ++i) {
            int li = t + i * 256;
            int r = li >> 3, k8 = (li & 7) * 8;
            int gr = row0 + r;
            if (gr >= NITEM) gr = NITEM - 1;
            const float* p = &F[(size_t)gr * DF + kc + k8];
            float4 f0 = *(const float4*)p;
            float4 f1 = *(const float4*)(p + 4);
            uint4 u;
            u.x = pack2(f0.x, f0.y); u.y = pack2(f0.z, f0.w);
            u.z = pack2(f1.x, f1.y); u.w = pack2(f1.z, f1.w);
            *(uint4*)&fa[r][k8] = u;
        }
        #pragma unroll
        for (int i = 0; i < 2; ++i) {
            int li = t + i * 256;
            int d = li >> 3, k8 = (li & 7) * 8;
            *(uint4*)&wb[d][k8] = *(const uint4*)&Wtb[(size_t)d * DF + kc + k8];
        }
        __syncthreads();
        #pragma unroll
        for (int k2 = 0; k2 < KC; k2 += 32) {
            union { uint4 u; bf16x8 v; } a;
            a.u = *(const uint4*)&fa[w * 16 + c][k2 + g * 8];
            #pragma unroll
            for (int ct = 0; ct < 4; ++ct) {
                union { uint4 u; bf16x8 v; } bb;
                bb.u = *(const uint4*)&wb[ct * 16 + c][k2 + g * 8];
                acc[ct] = __builtin_amdgcn_mfma_f32_16x16x32_bf16(a.v, bb.v, acc[ct], 0, 0, 0);
            }
        }
        __syncthreads();
    }

    int row_base = row0 + w * 16;
    #pragma unroll
    for (int ct = 0; ct < 4; ++ct) {
        float bc = B[ct * 16 + c];
        #pragma unroll
        for (int r = 0; r < 4; ++r) acc[ct][r] += bc;
    }
    float ssv[4];
    #pragma unroll
    for (int r = 0; r < 4; ++r) {
        float s = acc[0][r] * acc[0][r] + acc[1][r] * acc[1][r]
                + acc[2][r] * acc[2][r] + acc[3][r] * acc[3][r];
        #pragma unroll
        for (int m = 1; m <= 8; m <<= 1) s += __shfl_xor(s, m, 64);
        ssv[r] = 1.0f / fmaxf(sqrtf(s), 1e-12f);
    }
    #pragma unroll
    for (int r = 0; r < 4; ++r) {
        int gr = row_base + g * 4 + r;
        if (gr < NITEM) {
            size_t o = (size_t)(NUSER + gr) * DL + c;
            #pragma unroll
            for (int ct = 0; ct < 4; ++ct)
                e0[o + ct * 16] = bf16r(acc[ct][r] * ssv[r]);
        }
    }
}

// ---------------- pass 1: per-chunk histogram over row-bins (1024 threads) ----------------
__global__ __launch_bounds__(1024) void k_hist(const int* __restrict__ rows,
                                               int* __restrict__ cnt) {
    __shared__ int h[NB];
    int c = blockIdx.x, t = threadIdx.x;
    for (int i = t; i < NB; i += 1024) h[i] = 0;
    __syncthreads();
    int end = (c + 1) * CHUNK;
    for (int e = c * CHUNK + t; e < end; e += 1024)
        atomicAdd(&h[rows[e] >> 7], 1);
    __syncthreads();
    for (int i = t; i < NB; i += 1024) cnt[c * NB + i] = h[i];
}

// ---------------- pass 2a: per-bin exclusive scan over chunks ----------------
__global__ __launch_bounds__(256) void k_scan1(const int* __restrict__ cnt,
                                               int* __restrict__ cntOff,
                                               int* __restrict__ binTot) {
    __shared__ int s[256];
    int b = blockIdx.x, t = threadIdx.x;
    int x = cnt[t * NB + b];
    s[t] = x;
    __syncthreads();
    #pragma unroll
    for (int off = 1; off < 256; off <<= 1) {
        int v = (t >= off) ? s[t - off] : 0;
        __syncthreads();
        s[t] += v;
        __syncthreads();
    }
    cntOff[t * NB + b] = s[t] - x;
    if (t == 255) binTot[b] = s[255];
}

// ---------------- pass 2b: exclusive scan of bin totals ----------------
__global__ __launch_bounds__(256) void k_scan2(const int* __restrict__ binTot,
                                               int* __restrict__ binBase) {
    __shared__ int s[256];
    __shared__ int carry;
    int t = threadIdx.x;
    if (t == 0) carry = 0;
    __syncthreads();
    for (int base = 0; base < NB; base += 256) {
        int idx = base + t;
        int x = (idx < NB) ? binTot[idx] : 0;
        s[t] = x;
        __syncthreads();
        #pragma unroll
        for (int off = 1; off < 256; off <<= 1) {
            int v = (t >= off) ? s[t - off] : 0;
            __syncthreads();
            s[t] += v;
            __syncthreads();
        }
        if (idx < NB) binBase[idx] = carry + s[t] - x;
        __syncthreads();
        if (t == 255) carry += s[255];
        __syncthreads();
    }
    if (t == 0) binBase[NB] = carry;   // == NNZ
}

// ---------------- pass 3: scatter edges into bin-partitioned list (1024 threads) ----------------
__global__ __launch_bounds__(1024) void k_scatter(const int* __restrict__ rows,
                                                  const int* __restrict__ cols,
                                                  const float* __restrict__ vals,
                                                  const int* __restrict__ cntOff,
                                                  const int* __restrict__ binBase,
                                                  int2* __restrict__ eb) {
    __shared__ int cur[NB];
    int c = blockIdx.x, t = threadIdx.x;
    for (int i = t; i < NB; i += 1024) cur[i] = binBase[i] + cntOff[c * NB + i];
    __syncthreads();
    int end = (c + 1) * CHUNK;
    for (int e = c * CHUNK + t; e < end; e += 1024) {
        int r = rows[e];
        int b = r >> 7;
        int pos = atomicAdd(&cur[b], 1);
        eb[pos] = make_int2(cols[e] | ((r & 127) << 18), __float_as_int(vals[e]));
    }
}

// ---------------- pass 4: per-bin counting sort -> exact row-sorted CSR ----------------
__global__ __launch_bounds__(256) void k_binsort(const int2* __restrict__ eb,
                                                 const int* __restrict__ binBase,
                                                 int2* __restrict__ eb2,
                                                 int2* __restrict__ rowSC) {
    __shared__ int h[128];
    __shared__ int s[128];
    int b = blockIdx.x, t = threadIdx.x;
    if (t < 128) h[t] = 0;
    __syncthreads();
    int base = binBase[b];
    int cnt  = binBase[b + 1] - base;
    for (int j = t; j < cnt; j += 256)
        atomicAdd(&h[eb[base + j].x >> 18], 1);
    __syncthreads();
    if (t < 128) s[t] = h[t];
    __syncthreads();
    #pragma unroll
    for (int off = 1; off < 128; off <<= 1) {
        int v = 0;
        if (t < 128 && t >= off) v = s[t - off];
        __syncthreads();
        if (t < 128) s[t] += v;
        __syncthreads();
    }
    if (t < 128) {
        int e = s[t] - h[t];       // exclusive within-bin offset
        int r = (b << 7) + t;
        if (r < NTOT) rowSC[r] = make_int2(base + e, h[t]);
        s[t] = e;                  // becomes the cursor
    }
    __syncthreads();
    for (int j = t; j < cnt; j += 256) {
        int2 e = eb[base + j];
        int rl = e.x >> 18;
        int pos = base + atomicAdd(&s[rl], 1);
        eb2[pos] = make_int2(e.x & 0x3FFFF, e.y);
    }
}

#define SPMM_BODY(SRC)                                                              \
    int gt = blockIdx.x * 256 + threadIdx.x;                                        \
    int r  = gt >> 4;                                                               \
    if (r >= NTOT) return;                                                          \
    int lq = threadIdx.x & 15;                                                      \
    int2 sc = rowSC[r];                                                             \
    int j = sc.x, end = sc.x + sc.y;                                                \
    float a0 = 0.f, a1 = 0.f, a2 = 0.f, a3 = 0.f;                                   \
    int doff = lq * 4;                                                              \
    for (; j + 7 < end; j += 8) {                                                   \
        int2 e0_ = eb2[j],     e1_ = eb2[j + 1];                                    \
        int2 e2_ = eb2[j + 2], e3_ = eb2[j + 3];                                    \
        int2 e4_ = eb2[j + 4], e5_ = eb2[j + 5];                                    \
        int2 e6_ = eb2[j + 6], e7_ = eb2[j + 7];                                    \
        uint2 m0 = *(const uint2*)&SRC[e0_.x * DL + doff];                          \
        uint2 m1 = *(const uint2*)&SRC[e1_.x * DL + doff];                          \
        uint2 m2 = *(const uint2*)&SRC[e2_.x * DL + doff];                          \
        uint2 m3 = *(const uint2*)&SRC[e3_.x * DL + doff];                          \
        uint2 m4 = *(const uint2*)&SRC[e4_.x * DL + doff];                          \
        uint2 m5 = *(const uint2*)&SRC[e5_.x * DL + doff];                          \
        uint2 m6 = *(const uint2*)&SRC[e6_.x * DL + doff];                          \
        uint2 m7 = *(const uint2*)&SRC[e7_.x * DL + doff];                          \
        float v0 = __int_as_float(e0_.y), v1 = __int_as_float(e1_.y);               \
        float v2 = __int_as_float(e2_.y), v3 = __int_as_float(e3_.y);               \
        float v4 = __int_as_float(e4_.y), v5 = __int_as_float(e5_.y);               \
        float v6 = __int_as_float(e6_.y), v7 = __int_as_float(e7_.y);               \
        a0 += v0 * blo(m0.x); a1 += v0 * bhi(m0.x); a2 += v0 * blo(m0.y); a3 += v0 * bhi(m0.y); \
        a0 += v1 * blo(m1.x); a1 += v1 * bhi(m1.x); a2 += v1 * blo(m1.y); a3 += v1 * bhi(m1.y); \
        a0 += v2 * blo(m2.x); a1 += v2 * bhi(m2.x); a2 += v2 * blo(m2.y); a3 += v2 * bhi(m2.y); \
        a0 += v3 * blo(m3.x); a1 += v3 * bhi(m3.x); a2 += v3 * blo(m3.y); a3 += v3 * bhi(m3.y); \
        a0 += v4 * blo(m4.x); a1 += v4 * bhi(m4.x); a2 += v4 * blo(m4.y); a3 += v4 * bhi(m4.y); \
        a0 += v5 * blo(m5.x); a1 += v5 * bhi(m5.x); a2 += v5 * blo(m5.y); a3 += v5 * bhi(m5.y); \
        a0 += v6 * blo(m6.x); a1 += v6 * bhi(m6.x); a2 += v6 * blo(m6.y); a3 += v6 * bhi(m6.y); \
        a0 += v7 * blo(m7.x); a1 += v7 * bhi(m7.x); a2 += v7 * blo(m7.y); a3 += v7 * bhi(m7.y); \
    }                                                                               \
    for (; j + 1 < end; j += 2) {                                                   \
        int2 eA = eb2[j], eB = eb2[j + 1];                                          \
        uint2 mA = *(const uint2*)&SRC[eA.x * DL + doff];                           \
        uint2 mB = *(const uint2*)&SRC[eB.x * DL + doff];                           \
        float vA = __int_as_float(eA.y), vB = __int_as_float(eB.y);                 \
        a0 += vA * blo(mA.x); a1 += vA * bhi(mA.x); a2 += vA * blo(mA.y); a3 += vA * bhi(mA.y); \
        a0 += vB * blo(mB.x); a1 += vB * bhi(mB.x); a2 += vB * blo(mB.y); a3 += vB * bhi(mB.y); \
    }                                                                               \
    if (j < end) {                                                                  \
        int2 e = eb2[j];                                                            \
        uint2 m = *(const uint2*)&SRC[e.x * DL + doff];                             \
        float v = __int_as_float(e.y);                                              \
        a0 += v * blo(m.x); a1 += v * bhi(m.x); a2 += v * blo(m.y); a3 += v * bhi(m.y); \
    }

// ---------------- SpMM layer: 16 lanes per row, 8-wide pipeline ----------------
__global__ __launch_bounds__(256) void k_spmm_row(const int2* __restrict__ rowSC,
                                                  const int2* __restrict__ eb2,
                                                  const unsigned short* __restrict__ embIn,
                                                  unsigned short* __restrict__ embOut) {
    SPMM_BODY(embIn)
    uint2 o;
    o.x = pack2(a0, a1);
    o.y = pack2(a2, a3);
    *(uint2*)&embOut[r * DL + doff] = o;
}

// ---------------- last layer: same + fused out = 0.25*(e0+e1+e2+acc) ----------------
__global__ __launch_bounds__(256) void k_spmm_last(const int2* __restrict__ rowSC,
                                                   const int2* __restrict__ eb2,
                                                   const unsigned short* __restrict__ e0,
                                                   const unsigned short* __restrict__ e1,
                                                   const unsigned short* __restrict__ e2,
                                                   float* __restrict__ out) {
    SPMM_BODY(e2)
    int o = r * DL + doff;
    uint2 ua = *(const uint2*)&e0[o];
    uint2 ub = *(const uint2*)&e1[o];
    uint2 uc = *(const uint2*)&e2[o];
    float4 res;
    res.x = 0.25f * (blo(ua.x) + blo(ub.x) + blo(uc.x) + a0);
    res.y = 0.25f * (bhi(ua.x) + bhi(ub.x) + bhi(uc.x) + a1);
    res.z = 0.25f * (blo(ua.y) + blo(ub.y) + blo(uc.y) + a2);
    res.w = 0.25f * (bhi(ua.y) + bhi(ub.y) + bhi(uc.y) + a3);
    *(float4*)&out[o] = res;
}

extern "C" void kernel_launch(void* const* d_in, const int* in_sizes, int n_in,
                              void* d_out, int out_size, void* d_ws, size_t ws_size,
                              hipStream_t stream) {
    const float* F    = (const float*)d_in[0];
    const float* UP   = (const float*)d_in[1];
    const float* W    = (const float*)d_in[2];
    const float* B    = (const float*)d_in[3];
    const int*   rows = (const int*)d_in[4];
    const int*   cols = (const int*)d_in[5];
    const float* vals = (const float*)d_in[6];
    float* out = (float*)d_out;

    // workspace carve (~100 MB)
    unsigned short* e0 = (unsigned short*)d_ws;
    unsigned short* e1 = e0 + (size_t)NTOT * DL;
    unsigned short* e2 = e1 + (size_t)NTOT * DL;
    int2* eb      = (int2*)(e2 + (size_t)NTOT * DL);
    int2* eb2     = eb + (size_t)NNZ_;
    int2* rowSC   = eb2 + (size_t)NNZ_;
    int*  cnt     = (int*)(rowSC + NTOT);
    int*  cntOff  = cnt + (size_t)NCHUNK * NB;
    int*  binTot  = cntOff + (size_t)NCHUNK * NB;
    int*  binBase = binTot + NB;                      // NB+1 entries
    unsigned short* Wtb = (unsigned short*)(binBase + NB + 1);  // 64x512 bf16

    k_init<<<128 + (NUSER * DL) / 256, 256, 0, stream>>>(UP, W, e0, Wtb);
    k_item<<<(NITEM + 63) / 64, 256, 0, stream>>>(F, Wtb, B, e0);
    k_hist<<<NCHUNK, 1024, 0, stream>>>(rows, cnt);
    k_scan1<<<NB, 256, 0, stream>>>(cnt, cntOff, binTot);
    k_scan2<<<1, 256, 0, stream>>>(binTot, binBase);
    k_scatter<<<NCHUNK, 1024, 0, stream>>>(rows, cols, vals, cntOff, binBase, eb);
    k_binsort<<<NB, 256, 0, stream>>>(eb, binBase, eb2, rowSC);

    int spmm_blocks = (NTOT * 16 + 255) / 256;   // 16 threads per row
    k_spmm_row<<<spmm_blocks, 256, 0, stream>>>(rowSC, eb2, e0, e1);
    k_spmm_row<<<spmm_blocks, 256, 0, stream>>>(rowSC, eb2, e1, e2);
    k_spmm_last<<<spmm_blocks, 256, 0, stream>>>(rowSC, eb2, e0, e1, e2, out);
}